// Round 12
// baseline (243.932 us; speedup 1.0000x reference)
//
#include <hip/hip_runtime.h>

typedef __attribute__((ext_vector_type(8))) short bf16x8;
typedef __attribute__((ext_vector_type(4))) float f32x4;

__device__ __forceinline__ unsigned short f2bf(float f) {
  unsigned u = __builtin_bit_cast(unsigned, f);
  unsigned r = (u + 0x7FFFu + ((u >> 16) & 1u)) >> 16;
  return (unsigned short)r;
}
__device__ __forceinline__ float bf2f(unsigned short h) {
  return __builtin_bit_cast(float, (unsigned)h << 16);
}
__device__ __forceinline__ unsigned pack2(unsigned short a, unsigned short b) {
  return (unsigned)a | ((unsigned)b << 16);
}

__device__ __forceinline__ void gld_lds16(const void* g, void* l) {
  __builtin_amdgcn_global_load_lds(
      (const __attribute__((address_space(1))) unsigned int*)g,
      (__attribute__((address_space(3))) unsigned int*)l, 16, 0, 0);
}

#define SCHED0() __builtin_amdgcn_sched_barrier(0)
#define NTBAR() do { SCHED0(); __builtin_amdgcn_s_barrier(); SCHED0(); } while (0)
#define VMW(N) do { asm volatile("s_waitcnt vmcnt(" #N ")" ::: "memory"); SCHED0(); } while (0)
#define LGKM0() do { asm volatile("s_waitcnt lgkmcnt(0)" ::: "memory"); SCHED0(); } while (0)
#define MFMA16(a, b, c) __builtin_amdgcn_mfma_f32_16x16x32_bf16(a, b, c, 0, 0, 0)

// split 8 fp32 -> hi/lo bf16 fragments (register-resident), hi also returned raw
__device__ __forceinline__ void split8_frag(float4 v0, float4 v1,
                                            bf16x8* H, bf16x8* L,
                                            unsigned short hh[8]) {
  float f[8] = {v0.x, v0.y, v0.z, v0.w, v1.x, v1.y, v1.z, v1.w};
  unsigned short ll[8];
#pragma unroll
  for (int i = 0; i < 8; ++i) {
    hh[i] = f2bf(f[i]);
    ll[i] = f2bf(f[i] - bf2f(hh[i]));
  }
  uint4 hv = make_uint4(pack2(hh[0], hh[1]), pack2(hh[2], hh[3]),
                        pack2(hh[4], hh[5]), pack2(hh[6], hh[7]));
  uint4 lv = make_uint4(pack2(ll[0], ll[1]), pack2(ll[2], ll[3]),
                        pack2(ll[4], ll[5]), pack2(ll[6], ll[7]));
  *H = __builtin_bit_cast(bf16x8, hv);
  *L = __builtin_bit_cast(bf16x8, lv);
}

// -------- QB prep: Th/Tl[d][k] = split-bf16 of [Qm | Km] column d --------
__global__ __launch_bounds__(256) void qkm_split(const float* __restrict__ Qm,
                                                 const float* __restrict__ Km,
                                                 unsigned short* __restrict__ Th,
                                                 unsigned short* __restrict__ Tl) {
  __shared__ float lt[64][65];
  int k0 = blockIdx.x * 64;
  int half = blockIdx.y;
  const float* M = half ? Km : Qm;
  int t = threadIdx.x;
  int cl = (t & 15) * 4;
  int rl = t >> 4;
#pragma unroll
  for (int rr = 0; rr < 4; ++rr) {
    int r = rl + rr * 16;
    float4 v = *reinterpret_cast<const float4*>(&M[(long)(k0 + r) * 64 + cl]);
    lt[cl + 0][r] = v.x;
    lt[cl + 1][r] = v.y;
    lt[cl + 2][r] = v.z;
    lt[cl + 3][r] = v.w;
  }
  __syncthreads();
#pragma unroll
  for (int rr = 0; rr < 4; ++rr) {
    int c = rl + rr * 16;
    unsigned short h[4], lo[4];
#pragma unroll
    for (int i = 0; i < 4; ++i) {
      float f = lt[c][cl + i];
      h[i] = f2bf(f);
      lo[i] = f2bf(f - bf2f(h[i]));
    }
    *reinterpret_cast<uint2*>(&Th[(long)(half * 64 + c) * 1024 + k0 + cl]) =
        make_uint2(pack2(h[0], h[1]), pack2(h[2], h[3]));
    *reinterpret_cast<uint2*>(&Tl[(long)(half * 64 + c) * 1024 + k0 + cl]) =
        make_uint2(pack2(lo[0], lo[1]), pack2(lo[2], lo[3]));
  }
}

// ======== K1: barrier-free wave-independent split-bf16 MFMA =====================
// Each wave owns 32 x-rows x 128 d. Fragments loaded DIRECTLY from global:
//   A (Th/Tl, L2-resident): lane l <-> row l&15 (+16 per m), k-chunk (l>>4)*8 -> 16B
//   B (x, HBM):             lane l <-> row base+n*16+(l&15), same k-chunk (2 float4)
// x prefetched one K-tile ahead in registers. xbT transpose via per-wave LDS
// Tt[32][40] (chunk-XOR swizzle, ~2-way banks), wave-local lgkmcnt only.
// NO s_barrier anywhere.
__global__ __launch_bounds__(256) void k1_mfma(const float* __restrict__ x,
                                               const unsigned short* __restrict__ Th,
                                               const unsigned short* __restrict__ Tl,
                                               unsigned short* __restrict__ qkh,
                                               unsigned short* __restrict__ qkl,
                                               unsigned short* __restrict__ xbT) {
  __shared__ unsigned short Tt[4][32 * 40];
  const int t = threadIdx.x;
  const int l = t & 63;
  const int w = t >> 6;
  const long rowbase = ((long)blockIdx.x * 4 + w) * 32;
  const int b = (int)(rowbase >> 9);
  const int cB = (int)(rowbase & 511);
  unsigned short* Ttw = Tt[w];

  const int fr = l & 15;   // fragment row/col within 16
  const int fk = l >> 4;   // fragment k-chunk (x8)

  const float* xr0 = x + (rowbase + fr) * 1024 + fk * 8;
  const float* xr1 = x + (rowbase + 16 + fr) * 1024 + fk * 8;
  const unsigned short* ThF = Th + (long)fr * 1024 + fk * 8;
  const unsigned short* TlF = Tl + (long)fr * 1024 + fk * 8;

  f32x4 acc[8][2];
#pragma unroll
  for (int m = 0; m < 8; ++m)
#pragma unroll
    for (int n = 0; n < 2; ++n) acc[m][n] = (f32x4){0.f, 0.f, 0.f, 0.f};

  float4 xa0, xa1, xa2, xa3, xb0, xb1, xb2, xb3;
  xa0 = *reinterpret_cast<const float4*>(xr0);
  xa1 = *reinterpret_cast<const float4*>(xr0 + 4);
  xa2 = *reinterpret_cast<const float4*>(xr1);
  xa3 = *reinterpret_cast<const float4*>(xr1 + 4);

#define K1_BODY(ktc, XC0, XC1, XC2, XC3, XN0, XN1, XN2, XN3)                   \
  {                                                                            \
    const int ktn = ((ktc) + 1 < 32) ? (ktc) + 1 : 31;                         \
    uint4 ah[8], al[8];                                                        \
    _Pragma("unroll") for (int m = 0; m < 8; ++m) {                            \
      ah[m] = *reinterpret_cast<const uint4*>(ThF + (long)m * 16384 + (ktc) * 32); \
      al[m] = *reinterpret_cast<const uint4*>(TlF + (long)m * 16384 + (ktc) * 32); \
    }                                                                          \
    XN0 = *reinterpret_cast<const float4*>(xr0 + ktn * 32);                    \
    XN1 = *reinterpret_cast<const float4*>(xr0 + ktn * 32 + 4);                \
    XN2 = *reinterpret_cast<const float4*>(xr1 + ktn * 32);                    \
    XN3 = *reinterpret_cast<const float4*>(xr1 + ktn * 32 + 4);                \
    bf16x8 bh0, bl0, bh1, bl1;                                                 \
    unsigned short hh0[8], hh1[8];                                             \
    split8_frag(XC0, XC1, &bh0, &bl0, hh0);                                    \
    split8_frag(XC2, XC3, &bh1, &bl1, hh1);                                    \
    _Pragma("unroll") for (int i = 0; i < 8; ++i) {                            \
      int k = fk * 8 + i;                                                      \
      int s = (k >> 2) & 3;                                                    \
      Ttw[k * 40 + ((((fr >> 3)) ^ s) << 3) + (fr & 7)] = hh0[i];              \
      Ttw[k * 40 + (((2 + (fr >> 3)) ^ s) << 3) + (fr & 7)] = hh1[i];          \
    }                                                                          \
    _Pragma("unroll") for (int m = 0; m < 8; ++m) {                            \
      bf16x8 Ah = __builtin_bit_cast(bf16x8, ah[m]);                           \
      bf16x8 Al = __builtin_bit_cast(bf16x8, al[m]);                           \
      acc[m][0] = MFMA16(Ah, bh0, acc[m][0]);                                  \
      acc[m][0] = MFMA16(Ah, bl0, acc[m][0]);                                  \
      acc[m][0] = MFMA16(Al, bh0, acc[m][0]);                                  \
      acc[m][1] = MFMA16(Ah, bh1, acc[m][1]);                                  \
      acc[m][1] = MFMA16(Ah, bl1, acc[m][1]);                                  \
      acc[m][1] = MFMA16(Al, bh1, acc[m][1]);                                  \
    }                                                                          \
    LGKM0();                                                                   \
    {                                                                          \
      int k0 = l >> 2, ch = l & 3;                                             \
      int s0 = (k0 >> 2) & 3;                                                  \
      int k1i = k0 + 16;                                                       \
      int s1 = (k1i >> 2) & 3;                                                 \
      uint4 v0 = *reinterpret_cast<const uint4*>(&Ttw[k0 * 40 + ((ch ^ s0) << 3)]); \
      uint4 v1 = *reinterpret_cast<const uint4*>(&Ttw[k1i * 40 + ((ch ^ s1) << 3)]); \
      LGKM0();                                                                 \
      long basex = (long)b * 524288 + cB + ch * 8;                             \
      *reinterpret_cast<uint4*>(&xbT[basex + (long)((ktc) * 32 + k0) * 512]) = v0;  \
      *reinterpret_cast<uint4*>(&xbT[basex + (long)((ktc) * 32 + k1i) * 512]) = v1; \
    }                                                                          \
  }

  for (int kt = 0; kt < 32; kt += 2) {
    K1_BODY(kt, xa0, xa1, xa2, xa3, xb0, xb1, xb2, xb3);
    K1_BODY(kt + 1, xb0, xb1, xb2, xb3, xa0, xa1, xa2, xa3);
  }
#undef K1_BODY

  // epilogue: split acc -> qkh/qkl
#pragma unroll
  for (int m = 0; m < 8; ++m)
#pragma unroll
    for (int n = 0; n < 2; ++n) {
      int d0 = m * 16 + (l >> 4) * 4;
      long xr = rowbase + n * 16 + (l & 15);
      unsigned short h4[4], l4[4];
#pragma unroll
      for (int reg = 0; reg < 4; ++reg) {
        float v = acc[m][n][reg];
        h4[reg] = f2bf(v);
        l4[reg] = f2bf(v - bf2f(h4[reg]));
      }
      *reinterpret_cast<uint2*>(&qkh[xr * 128 + d0]) =
          make_uint2(pack2(h4[0], h4[1]), pack2(h4[2], h4[3]));
      *reinterpret_cast<uint2*>(&qkl[xr * 128 + d0]) =
          make_uint2(pack2(l4[0], l4[1]), pack2(l4[2], l4[3]));
    }
}

// -------- K2a: st[b,j,i] = exp(sigmoid(q_i . k_j)), split-bf16 MFMA -----------
// Stages pre-split qkh/qkl via global_load_lds (lane-linear dest, swizzled src).
__global__ __launch_bounds__(256) void k2a_mfma(const unsigned short* __restrict__ qkh,
                                                const unsigned short* __restrict__ qkl,
                                                unsigned short* __restrict__ st) {
  __shared__ unsigned short Ah[128 * 64];
  __shared__ unsigned short Al[128 * 64];
  __shared__ unsigned short Bh[128 * 64];
  __shared__ unsigned short Bl[128 * 64];
  const int t = threadIdx.x;
  const int l = t & 63;
  const int w = t >> 6;
  const int wr = w >> 1, wc = w & 1;

  const int cpx = gridDim.x >> 3;
  const int orig = blockIdx.x;
  const int lw = (orig & 7) * cpx + (orig >> 3);
  const int b = lw >> 4;
  const int tile = lw & 15;
  const int iBase = (tile >> 2) * 128;
  const int jBase = (tile & 3) * 128;
  const long bq = (long)b * 512;

  const int sg = (l & 7) ^ (l >> 3);
#pragma unroll
  for (int c4 = 0; c4 < 4; ++c4) {
    int rb = w * 32 + c4 * 8;
    long rowA = bq + iBase + rb + (l >> 3);
    long rowB = bq + jBase + rb + (l >> 3);
    gld_lds16(qkh + rowA * 128 + sg * 8, &Ah[rb * 64]);
    gld_lds16(qkl + rowA * 128 + sg * 8, &Al[rb * 64]);
    gld_lds16(qkh + rowB * 128 + 64 + sg * 8, &Bh[rb * 64]);
    gld_lds16(qkl + rowB * 128 + 64 + sg * 8, &Bl[rb * 64]);
  }
  __syncthreads();

  f32x4 acc[4][4];
#pragma unroll
  for (int m = 0; m < 4; ++m)
#pragma unroll
    for (int n = 0; n < 4; ++n) acc[m][n] = (f32x4){0.f, 0.f, 0.f, 0.f};

#pragma unroll
  for (int ks = 0; ks < 2; ++ks) {
    bf16x8 ah[4], al4[4], bh[4], bl4[4];
#pragma unroll
    for (int m = 0; m < 4; ++m) {
      int row = wr * 64 + m * 16 + (l & 15);
      int off = row * 64 + ((ks * 4 + (l >> 4)) ^ (row & 7)) * 8;
      ah[m] = *reinterpret_cast<const bf16x8*>(&Ah[off]);
      al4[m] = *reinterpret_cast<const bf16x8*>(&Al[off]);
    }
#pragma unroll
    for (int n = 0; n < 4; ++n) {
      int row = wc * 64 + n * 16 + (l & 15);
      int off = row * 64 + ((ks * 4 + (l >> 4)) ^ (row & 7)) * 8;
      bh[n] = *reinterpret_cast<const bf16x8*>(&Bh[off]);
      bl4[n] = *reinterpret_cast<const bf16x8*>(&Bl[off]);
    }
#pragma unroll
    for (int m = 0; m < 4; ++m)
#pragma unroll
      for (int n = 0; n < 4; ++n) {
        acc[m][n] = MFMA16(ah[m], bh[n], acc[m][n]);
        acc[m][n] = MFMA16(ah[m], bl4[n], acc[m][n]);
        acc[m][n] = MFMA16(al4[m], bh[n], acc[m][n]);
      }
  }

  unsigned short* sb = st + (long)b * 512 * 512;
#pragma unroll
  for (int m = 0; m < 4; ++m)
#pragma unroll
    for (int n = 0; n < 4; ++n) {
      int i0 = iBase + wr * 64 + m * 16 + (l >> 4) * 4;
      int j = jBase + wc * 64 + n * 16 + (l & 15);
      unsigned short p[4];
#pragma unroll
      for (int reg = 0; reg < 4; ++reg) {
        float sg2 = 1.0f / (1.0f + __expf(-acc[m][n][reg]));
        p[reg] = f2bf(__expf(sg2));
      }
      *reinterpret_cast<uint2*>(&sb[(long)j * 512 + i0]) = *reinterpret_cast<uint2*>(p);
    }
}

// -------- K2b: per-row (j) sums of st -> rsum = 1/sum, attbias = (st.bias)/sum ----
__global__ __launch_bounds__(256) void k2b_rsum(const unsigned short* __restrict__ st,
                                                const float* __restrict__ bias,
                                                float* __restrict__ rsum,
                                                float* __restrict__ attbias) {
  int jg = blockIdx.x * 4 + (threadIdx.x >> 6);
  int l = threadIdx.x & 63;
  const unsigned short* row = st + (long)jg * 512 + l * 8;
  ushort4 u0 = *reinterpret_cast<const ushort4*>(row);
  ushort4 u1 = *reinterpret_cast<const ushort4*>(row + 4);
  float4 b0 = *reinterpret_cast<const float4*>(&bias[l * 8]);
  float4 b1 = *reinterpret_cast<const float4*>(&bias[l * 8 + 4]);
  float f0 = bf2f(u0.x), f1 = bf2f(u0.y), f2 = bf2f(u0.z), f3 = bf2f(u0.w);
  float f4 = bf2f(u1.x), f5 = bf2f(u1.y), f6 = bf2f(u1.z), f7 = bf2f(u1.w);
  float sum = (f0 + f1) + (f2 + f3) + ((f4 + f5) + (f6 + f7));
  float sumb = f0 * b0.x + f1 * b0.y + f2 * b0.z + f3 * b0.w +
               f4 * b1.x + f5 * b1.y + f6 * b1.z + f7 * b1.w;
#pragma unroll
  for (int off = 32; off > 0; off >>= 1) {
    sum += __shfl_down(sum, off);
    sumb += __shfl_down(sumb, off);
  }
  if (l == 0) {
    float r = 1.0f / sum;
    rsum[jg] = r;
    attbias[jg] = sumb * r;
  }
}

// -------- transpose + fp32->bf16 convert: out[c][r] = bf16(in[r][c]) --------
__global__ __launch_bounds__(256) void transpose_conv(const float* __restrict__ in,
                                                      unsigned short* __restrict__ out,
                                                      int inRows, int inCols,
                                                      long inBatch, long outBatch) {
  __shared__ unsigned short lt[64][65];
  int b = blockIdx.z;
  int r0 = blockIdx.y * 64;
  int c0 = blockIdx.x * 64;
  const float* I = in + (long)b * inBatch;
  unsigned short* O = out + (long)b * outBatch;
  int t = threadIdx.x;
  int cl = (t & 15) * 4;
  int rl = t >> 4;
#pragma unroll
  for (int rr = 0; rr < 4; ++rr) {
    int r = rl + rr * 16;
    float4 v = *reinterpret_cast<const float4*>(&I[(long)(r0 + r) * inCols + c0 + cl]);
    lt[cl + 0][r] = f2bf(v.x);
    lt[cl + 1][r] = f2bf(v.y);
    lt[cl + 2][r] = f2bf(v.z);
    lt[cl + 3][r] = f2bf(v.w);
  }
  __syncthreads();
#pragma unroll
  for (int rr = 0; rr < 4; ++rr) {
    int c = rl + rr * 16;
    unsigned short v[4] = {lt[c][cl], lt[c][cl + 1], lt[c][cl + 2], lt[c][cl + 3]};
    *reinterpret_cast<uint2*>(&O[(long)(c0 + c) * inRows + r0 + cl]) =
        *reinterpret_cast<uint2*>(&v[0]);
  }
}

// ======== 256x256 bf16 MFMA GEMM, BK=64, 8 waves, 8-PHASE schedule (m201) ========
template <int MODE>
__global__ __launch_bounds__(512) void mfma_nt256(const unsigned short* __restrict__ Abase,
                                                  const unsigned short* __restrict__ Bbase,
                                                  const float* __restrict__ rowscale,
                                                  unsigned short* __restrict__ Wout,
                                                  float* __restrict__ Fout) {
  __shared__ unsigned short As[2][256 * 64];
  __shared__ unsigned short Bs[2][256 * 64];
  const int t = threadIdx.x;
  const int l = t & 63;
  const int w = t >> 6;          // 0..7
  const int wr = w >> 2;         // 0..1  (M: 2 x 128)
  const int wc = w & 3;          // 0..3  (N: 4 x 64)

  const int cpx = gridDim.x >> 3;
  const int orig = blockIdx.x;
  const int lw = (orig & 7) * cpx + (orig >> 3);
  const int TPB_SH = (MODE == 0) ? 2 : 3;
  const int b = lw >> TPB_SH;
  const int tile = lw & ((1 << TPB_SH) - 1);
  const int mBase = (tile >> 1) * 256;
  const int nBase = (tile & 1) * 256;

  const unsigned short* Ag = Abase + ((MODE == 0) ? 0L : (long)b * (1024 * 512)) + (long)mBase * 512;
  const unsigned short* Bg = Bbase + (long)b * (512 * 512) + (long)nBase * 512;

  f32x4 acc[8][4];
#pragma unroll
  for (int m = 0; m < 8; ++m)
#pragma unroll
    for (int n = 0; n < 4; ++n) acc[m][n] = (f32x4){0.f, 0.f, 0.f, 0.f};

  const int srcslot = (l & 7) ^ (l >> 3);
  const int so0 = ((l >> 4) ^ (l & 7)) * 8;
  const int so1 = ((4 + (l >> 4)) ^ (l & 7)) * 8;

#define STG_A(p, tt, pr)                                                       \
  gld_lds16(Ag + (long)((pr) * 64 + w * 8 + (l >> 3)) * 512 + (tt) * 64 + srcslot * 8, \
            &As[p][((pr) * 64 + w * 8) * 64]);
#define STG_B(p, tt, pr)                                                       \
  gld_lds16(Bg + (long)((pr) * 64 + w * 8 + (l >> 3)) * 512 + (tt) * 64 + srcslot * 8, \
            &Bs[p][((pr) * 64 + w * 8) * 64]);

#define PHASE(p, q, STAGE_STMT, VMSTMT)                                        \
  {                                                                            \
    bf16x8 a00 = *reinterpret_cast<const bf16x8*>(                             \
        &As[p][(wr * 128 + (2 * (q)) * 16 + (l & 15)) * 64 + so0]);            \
    bf16x8 a01 = *reinterpret_cast<const bf16x8*>(                             \
        &As[p][(wr * 128 + (2 * (q)) * 16 + (l & 15)) * 64 + so1]);            \
    bf16x8 a10 = *reinterpret_cast<const bf16x8*>(                             \
        &As[p][(wr * 128 + (2 * (q) + 1) * 16 + (l & 15)) * 64 + so0]);        \
    bf16x8 a11 = *reinterpret_cast<const bf16x8*>(                             \
        &As[p][(wr * 128 + (2 * (q) + 1) * 16 + (l & 15)) * 64 + so1]);        \
    if ((q) == 0) {                                                            \
      _Pragma("unroll") for (int n = 0; n < 4; ++n) {                          \
        bfr0[n] = *reinterpret_cast<const bf16x8*>(                            \
            &Bs[p][(wc * 64 + n * 16 + (l & 15)) * 64 + so0]);                 \
        bfr1[n] = *reinterpret_cast<const bf16x8*>(                            \
            &Bs[p][(wc * 64 + n * 16 + (l & 15)) * 64 + so1]);                 \
      }                                                                        \
    }                                                                          \
    STAGE_STMT;                                                                \
    SCHED0();                                                                  \
    __builtin_amdgcn_s_barrier();                                              \
    LGKM0();                                                                   \
    __builtin_amdgcn_s_setprio(1);                                             \
    _Pragma("unroll") for (int n = 0; n < 4; ++n) {                            \
      acc[2 * (q)][n] = MFMA16(a00, bfr0[n], acc[2 * (q)][n]);                 \
      acc[2 * (q)][n] = MFMA16(a01, bfr1[n], acc[2 * (q)][n]);                 \
      acc[2 * (q) + 1][n] = MFMA16(a10, bfr0[n], acc[2 * (q) + 1][n]);         \
      acc[2 * (q) + 1][n] = MFMA16(a11, bfr1[n], acc[2 * (q) + 1][n]);         \
    }                                                                          \
    __builtin_amdgcn_s_setprio(0);                                             \
    VMSTMT;                                                                    \
    NTBAR();                                                                   \
  }

  bf16x8 bfr0[4], bfr1[4];

  // prologue: buf0 <- tile0 (8 loads), buf1 <- B0,B1,Ha of tile1 (6 loads)
  STG_A(0, 0, 0); STG_A(0, 0, 1); STG_A(0, 0, 2); STG_A(0, 0, 3);
  STG_B(0, 0, 0); STG_B(0, 0, 1); STG_B(0, 0, 2); STG_B(0, 0, 3);
  STG_B(1, 1, 0); STG_B(1, 1, 1); STG_B(1, 1, 2); STG_B(1, 1, 3);
  STG_A(1, 1, 0); STG_A(1, 1, 2);
  VMW(6);
  NTBAR();

  for (int it = 0; it < 4; ++it) {
    const int t1 = 2 * it + 1;
    const int t2 = (2 * it + 2 < 8) ? 2 * it + 2 : 7;
    const int t3 = (2 * it + 3 < 8) ? 2 * it + 3 : 7;
    PHASE(0, 0, { STG_A(1, t1, 1); STG_A(1, t1, 3); }, );
    PHASE(0, 1, { STG_B(0, t2, 0); STG_B(0, t2, 1); }, VMW(10));
    PHASE(0, 2, { STG_B(0, t2, 2); STG_B(0, t2, 3); }, );
    PHASE(0, 3, { STG_A(0, t2, 0); STG_A(0, t2, 2); }, VMW(8));
    PHASE(1, 0, { STG_A(0, t2, 1); STG_A(0, t2, 3); }, );
    PHASE(1, 1, { STG_B(1, t3, 0); STG_B(1, t3, 1); }, VMW(10));
    PHASE(1, 2, { STG_B(1, t3, 2); STG_B(1, t3, 3); }, );
    PHASE(1, 3, { STG_A(1, t3, 0); STG_A(1, t3, 2); }, VMW(8));
  }
#undef PHASE
#undef STG_A
#undef STG_B

  if (MODE == 0) {
    unsigned short* W = Wout + (long)b * (512 * 512);
#pragma unroll
    for (int n = 0; n < 4; ++n) {
      int j = nBase + wc * 64 + n * 16 + (l & 15);
      float rs = rowscale[b * 512 + j];
#pragma unroll
      for (int m = 0; m < 8; ++m) {
        int c0 = mBase + wr * 128 + m * 16 + (l >> 4) * 4;
        unsigned short p[4];
#pragma unroll
        for (int reg = 0; reg < 4; ++reg) p[reg] = f2bf(acc[m][n][reg] * rs);
        *reinterpret_cast<uint2*>(&W[(long)j * 512 + c0]) = *reinterpret_cast<uint2*>(p);
      }
    }
  } else {
    float* O = Fout + (long)b * (512 * 1024);
#pragma unroll
    for (int n = 0; n < 4; ++n) {
      int j = nBase + wc * 64 + n * 16 + (l & 15);
      float ab = rowscale[b * 512 + j];
#pragma unroll
      for (int m = 0; m < 8; ++m) {
        int n0 = mBase + wr * 128 + m * 16 + (l >> 4) * 4;
        *reinterpret_cast<float4*>(&O[(long)j * 1024 + n0]) =
            make_float4(acc[m][n][0] + ab, acc[m][n][1] + ab,
                        acc[m][n][2] + ab, acc[m][n][3] + ab);
      }
    }
  }
}

extern "C" void kernel_launch(void* const* d_in, const int* in_sizes, int n_in,
                              void* d_out, int out_size, void* d_ws, size_t ws_size,
                              hipStream_t stream) {
  const float* x  = (const float*)d_in[0];
  const float* Qm = (const float*)d_in[1];
  const float* Km = (const float*)d_in[2];
  const float* vw = (const float*)d_in[3];
  const float* vb = (const float*)d_in[4];
  float* out = (float*)d_out;

  float* ws = (float*)d_ws;
  unsigned short* qkh  = (unsigned short*)ws;                         // 4,194,304 ush
  unsigned short* qkl  = qkh + 4194304;                               // 4,194,304 ush
  unsigned short* st   = (unsigned short*)(ws + 4194304);             // spans 8,388,608 f
  unsigned short* weff = (unsigned short*)(ws + 4194304 + 8388608);   // spans 8,388,608 f
  unsigned short* xbT  = (unsigned short*)(ws + 4194304 + 16777216);  // spans 16,777,216 f
  unsigned short* vwT  = (unsigned short*)(ws + 4194304 + 33554432);  // spans 131,072 f
  unsigned short* qkTh = (unsigned short*)(ws + 4194304 + 33554432 + 131072);  // 65,536 f
  unsigned short* qkTl = qkTh + 131072;                               // 65,536 f
  float* rsum    = ws + 4194304 + 33554432 + 131072 + 131072;         // 32,768 f
  float* attbias = rsum + 32768;                                      // 32,768 f

  // T2: vwT[c][i] = bf16(vw[i][c])
  transpose_conv<<<dim3(8, 8, 1), 256, 0, stream>>>(vw, vwT, 512, 512, 0L, 0L);
  // T3: split-transposed [Qm|Km] -> qkTh/qkTl [128][1024]
  qkm_split<<<dim3(16, 2), 256, 0, stream>>>(Qm, Km, qkTh, qkTl);
  // K1: qkh/qkl = split(x @ [Qm|Km]) + fused xbT transpose (barrier-free waves)
  k1_mfma<<<256, 256, 0, stream>>>(x, qkTh, qkTl, qkh, qkl, xbT);
  // K2a: st[b,j,i] = exp(sigmoid(q_i . k_j)), gld_lds staging of qkh/qkl
  k2a_mfma<<<1024, 256, 0, stream>>>(qkh, qkl, st);
  // K2b: rsum, attbias
  k2b_rsum<<<8192, 256, 0, stream>>>(st, vb, rsum, attbias);
  // K3: weff = diag(rsum) . st . Vw   (A=vwT, B=st), 4 tiles/b
  mfma_nt256<0><<<256, 512, 0, stream>>>(vwT, st, rsum, weff, nullptr);
  // K4: out = weff . xf + attbias     (A=xbT, B=weff), 8 tiles/b
  mfma_nt256<1><<<512, 512, 0, stream>>>(xbT, weff, attbias, nullptr, out);
}

// Round 13
// 239.575 us; speedup vs baseline: 1.0182x; 1.0182x over previous
//
#include <hip/hip_runtime.h>

typedef __attribute__((ext_vector_type(8))) short bf16x8;
typedef __attribute__((ext_vector_type(4))) float f32x4;

__device__ __forceinline__ unsigned short f2bf(float f) {
  unsigned u = __builtin_bit_cast(unsigned, f);
  unsigned r = (u + 0x7FFFu + ((u >> 16) & 1u)) >> 16;
  return (unsigned short)r;
}
__device__ __forceinline__ float bf2f(unsigned short h) {
  return __builtin_bit_cast(float, (unsigned)h << 16);
}
__device__ __forceinline__ unsigned pack2(unsigned short a, unsigned short b) {
  return (unsigned)a | ((unsigned)b << 16);
}

__device__ __forceinline__ void gld_lds16(const void* g, void* l) {
  __builtin_amdgcn_global_load_lds(
      (const __attribute__((address_space(1))) unsigned int*)g,
      (__attribute__((address_space(3))) unsigned int*)l, 16, 0, 0);
}

#define SCHED0() __builtin_amdgcn_sched_barrier(0)
#define NTBAR() do { SCHED0(); __builtin_amdgcn_s_barrier(); SCHED0(); } while (0)
#define VMW(N) do { asm volatile("s_waitcnt vmcnt(" #N ")" ::: "memory"); SCHED0(); } while (0)
#define LGKM0() do { asm volatile("s_waitcnt lgkmcnt(0)" ::: "memory"); SCHED0(); } while (0)
#define MFMA16(a, b, c) __builtin_amdgcn_mfma_f32_16x16x32_bf16(a, b, c, 0, 0, 0)

// split 8 fp32 -> hi/lo bf16 fragments (register-resident), hi also returned raw
__device__ __forceinline__ void split8_frag(float4 v0, float4 v1,
                                            bf16x8* H, bf16x8* L,
                                            unsigned short hh[8]) {
  float f[8] = {v0.x, v0.y, v0.z, v0.w, v1.x, v1.y, v1.z, v1.w};
  unsigned short ll[8];
#pragma unroll
  for (int i = 0; i < 8; ++i) {
    hh[i] = f2bf(f[i]);
    ll[i] = f2bf(f[i] - bf2f(hh[i]));
  }
  uint4 hv = make_uint4(pack2(hh[0], hh[1]), pack2(hh[2], hh[3]),
                        pack2(hh[4], hh[5]), pack2(hh[6], hh[7]));
  uint4 lv = make_uint4(pack2(ll[0], ll[1]), pack2(ll[2], ll[3]),
                        pack2(ll[4], ll[5]), pack2(ll[6], ll[7]));
  *H = __builtin_bit_cast(bf16x8, hv);
  *L = __builtin_bit_cast(bf16x8, lv);
}

// -------- QB prep: Th/Tl[d][k] = split-bf16 of [Qm | Km] column d --------
__global__ __launch_bounds__(256) void qkm_split(const float* __restrict__ Qm,
                                                 const float* __restrict__ Km,
                                                 unsigned short* __restrict__ Th,
                                                 unsigned short* __restrict__ Tl) {
  __shared__ float lt[64][65];
  int k0 = blockIdx.x * 64;
  int half = blockIdx.y;
  const float* M = half ? Km : Qm;
  int t = threadIdx.x;
  int cl = (t & 15) * 4;
  int rl = t >> 4;
#pragma unroll
  for (int rr = 0; rr < 4; ++rr) {
    int r = rl + rr * 16;
    float4 v = *reinterpret_cast<const float4*>(&M[(long)(k0 + r) * 64 + cl]);
    lt[cl + 0][r] = v.x;
    lt[cl + 1][r] = v.y;
    lt[cl + 2][r] = v.z;
    lt[cl + 3][r] = v.w;
  }
  __syncthreads();
#pragma unroll
  for (int rr = 0; rr < 4; ++rr) {
    int c = rl + rr * 16;
    unsigned short h[4], lo[4];
#pragma unroll
    for (int i = 0; i < 4; ++i) {
      float f = lt[c][cl + i];
      h[i] = f2bf(f);
      lo[i] = f2bf(f - bf2f(h[i]));
    }
    *reinterpret_cast<uint2*>(&Th[(long)(half * 64 + c) * 1024 + k0 + cl]) =
        make_uint2(pack2(h[0], h[1]), pack2(h[2], h[3]));
    *reinterpret_cast<uint2*>(&Tl[(long)(half * 64 + c) * 1024 + k0 + cl]) =
        make_uint2(pack2(lo[0], lo[1]), pack2(lo[2], lo[3]));
  }
}

// ======== K1: barrier-free wave-independent split-bf16 MFMA (occupancy-fixed) ====
// Block = 4 waves = 2 row-groups (32 x-rows each) x 2 d-halves (64 d each).
// Wave computes 32 rows x 64 d: acc[4][2], A-frags 4m x hi/lo (32 VGPR),
// grid 512 -> 2048 waves (2/SIMD). Fragments loaded DIRECTLY from global
// (Th/Tl L2-resident; x HBM, d-half pair reads same lines -> L1 hit).
// xbT transpose: d-half-0 waves only, per-wave LDS Tt (chunk-XOR swizzle),
// wave-local lgkmcnt only. NO s_barrier anywhere.
__global__ __launch_bounds__(256) void k1_mfma(const float* __restrict__ x,
                                               const unsigned short* __restrict__ Th,
                                               const unsigned short* __restrict__ Tl,
                                               unsigned short* __restrict__ qkh,
                                               unsigned short* __restrict__ qkl,
                                               unsigned short* __restrict__ xbT) {
  __shared__ unsigned short Tt[2][32 * 40];
  const int t = threadIdx.x;
  const int l = t & 63;
  const int w = t >> 6;
  const int rg = w >> 1;       // row-group 0/1 (32 rows each)
  const int dh = w & 1;        // d-half 0/1 (64 d each)
  const long rowW = (long)blockIdx.x * 64 + rg * 32;
  const int b = (int)(rowW >> 9);
  const int cB = (int)(rowW & 511);
  unsigned short* Ttw = Tt[rg];

  const int fr = l & 15;   // fragment row/col within 16
  const int fk = l >> 4;   // fragment k-chunk (x8)

  const float* xr0 = x + (rowW + fr) * 1024 + fk * 8;
  const float* xr1 = x + (rowW + 16 + fr) * 1024 + fk * 8;
  const unsigned short* ThF = Th + (long)(dh * 64 + fr) * 1024 + fk * 8;
  const unsigned short* TlF = Tl + (long)(dh * 64 + fr) * 1024 + fk * 8;

  f32x4 acc[4][2];
#pragma unroll
  for (int m = 0; m < 4; ++m)
#pragma unroll
    for (int n = 0; n < 2; ++n) acc[m][n] = (f32x4){0.f, 0.f, 0.f, 0.f};

  float4 xa0, xa1, xa2, xa3, xb0, xb1, xb2, xb3;
  xa0 = *reinterpret_cast<const float4*>(xr0);
  xa1 = *reinterpret_cast<const float4*>(xr0 + 4);
  xa2 = *reinterpret_cast<const float4*>(xr1);
  xa3 = *reinterpret_cast<const float4*>(xr1 + 4);

#define K1_BODY(ktc, XC0, XC1, XC2, XC3, XN0, XN1, XN2, XN3)                   \
  {                                                                            \
    const int ktn = ((ktc) + 1 < 32) ? (ktc) + 1 : 31;                         \
    uint4 ah[4], al[4];                                                        \
    _Pragma("unroll") for (int m = 0; m < 4; ++m) {                            \
      ah[m] = *reinterpret_cast<const uint4*>(ThF + (long)m * 16384 + (ktc) * 32); \
      al[m] = *reinterpret_cast<const uint4*>(TlF + (long)m * 16384 + (ktc) * 32); \
    }                                                                          \
    XN0 = *reinterpret_cast<const float4*>(xr0 + ktn * 32);                    \
    XN1 = *reinterpret_cast<const float4*>(xr0 + ktn * 32 + 4);                \
    XN2 = *reinterpret_cast<const float4*>(xr1 + ktn * 32);                    \
    XN3 = *reinterpret_cast<const float4*>(xr1 + ktn * 32 + 4);                \
    bf16x8 bh0, bl0, bh1, bl1;                                                 \
    unsigned short hh0[8], hh1[8];                                             \
    split8_frag(XC0, XC1, &bh0, &bl0, hh0);                                    \
    split8_frag(XC2, XC3, &bh1, &bl1, hh1);                                    \
    if (dh == 0) {                                                             \
      _Pragma("unroll") for (int i = 0; i < 8; ++i) {                          \
        int k = fk * 8 + i;                                                    \
        int s = (k >> 2) & 3;                                                  \
        Ttw[k * 40 + ((((fr >> 3)) ^ s) << 3) + (fr & 7)] = hh0[i];            \
        Ttw[k * 40 + (((2 + (fr >> 3)) ^ s) << 3) + (fr & 7)] = hh1[i];        \
      }                                                                        \
    }                                                                          \
    _Pragma("unroll") for (int m = 0; m < 4; ++m) {                            \
      bf16x8 Ah = __builtin_bit_cast(bf16x8, ah[m]);                           \
      bf16x8 Al = __builtin_bit_cast(bf16x8, al[m]);                           \
      acc[m][0] = MFMA16(Ah, bh0, acc[m][0]);                                  \
      acc[m][0] = MFMA16(Ah, bl0, acc[m][0]);                                  \
      acc[m][0] = MFMA16(Al, bh0, acc[m][0]);                                  \
      acc[m][1] = MFMA16(Ah, bh1, acc[m][1]);                                  \
      acc[m][1] = MFMA16(Ah, bl1, acc[m][1]);                                  \
      acc[m][1] = MFMA16(Al, bh1, acc[m][1]);                                  \
    }                                                                          \
    if (dh == 0) {                                                             \
      LGKM0();                                                                 \
      int k0 = l >> 2, ch = l & 3;                                             \
      int s0 = (k0 >> 2) & 3;                                                  \
      int k1i = k0 + 16;                                                       \
      int s1 = (k1i >> 2) & 3;                                                 \
      uint4 v0 = *reinterpret_cast<const uint4*>(&Ttw[k0 * 40 + ((ch ^ s0) << 3)]); \
      uint4 v1 = *reinterpret_cast<const uint4*>(&Ttw[k1i * 40 + ((ch ^ s1) << 3)]); \
      LGKM0();                                                                 \
      long basex = (long)b * 524288 + cB + ch * 8;                             \
      *reinterpret_cast<uint4*>(&xbT[basex + (long)((ktc) * 32 + k0) * 512]) = v0;  \
      *reinterpret_cast<uint4*>(&xbT[basex + (long)((ktc) * 32 + k1i) * 512]) = v1; \
    }                                                                          \
  }

  for (int kt = 0; kt < 32; kt += 2) {
    K1_BODY(kt, xa0, xa1, xa2, xa3, xb0, xb1, xb2, xb3);
    K1_BODY(kt + 1, xb0, xb1, xb2, xb3, xa0, xa1, xa2, xa3);
  }
#undef K1_BODY

  // epilogue: split acc -> qkh/qkl (wave's 32 rows x 64 d)
#pragma unroll
  for (int m = 0; m < 4; ++m)
#pragma unroll
    for (int n = 0; n < 2; ++n) {
      int d0 = dh * 64 + m * 16 + (l >> 4) * 4;
      long xr = rowW + n * 16 + (l & 15);
      unsigned short h4[4], l4[4];
#pragma unroll
      for (int reg = 0; reg < 4; ++reg) {
        float v = acc[m][n][reg];
        h4[reg] = f2bf(v);
        l4[reg] = f2bf(v - bf2f(h4[reg]));
      }
      *reinterpret_cast<uint2*>(&qkh[xr * 128 + d0]) =
          make_uint2(pack2(h4[0], h4[1]), pack2(h4[2], h4[3]));
      *reinterpret_cast<uint2*>(&qkl[xr * 128 + d0]) =
          make_uint2(pack2(l4[0], l4[1]), pack2(l4[2], l4[3]));
    }
}

// -------- K2a: st[b,j,i] = exp(sigmoid(q_i . k_j)), split-bf16 MFMA -----------
// Stages pre-split qkh/qkl via global_load_lds (lane-linear dest, swizzled src).
__global__ __launch_bounds__(256) void k2a_mfma(const unsigned short* __restrict__ qkh,
                                                const unsigned short* __restrict__ qkl,
                                                unsigned short* __restrict__ st) {
  __shared__ unsigned short Ah[128 * 64];
  __shared__ unsigned short Al[128 * 64];
  __shared__ unsigned short Bh[128 * 64];
  __shared__ unsigned short Bl[128 * 64];
  const int t = threadIdx.x;
  const int l = t & 63;
  const int w = t >> 6;
  const int wr = w >> 1, wc = w & 1;

  const int cpx = gridDim.x >> 3;
  const int orig = blockIdx.x;
  const int lw = (orig & 7) * cpx + (orig >> 3);
  const int b = lw >> 4;
  const int tile = lw & 15;
  const int iBase = (tile >> 2) * 128;
  const int jBase = (tile & 3) * 128;
  const long bq = (long)b * 512;

  const int sg = (l & 7) ^ (l >> 3);
#pragma unroll
  for (int c4 = 0; c4 < 4; ++c4) {
    int rb = w * 32 + c4 * 8;
    long rowA = bq + iBase + rb + (l >> 3);
    long rowB = bq + jBase + rb + (l >> 3);
    gld_lds16(qkh + rowA * 128 + sg * 8, &Ah[rb * 64]);
    gld_lds16(qkl + rowA * 128 + sg * 8, &Al[rb * 64]);
    gld_lds16(qkh + rowB * 128 + 64 + sg * 8, &Bh[rb * 64]);
    gld_lds16(qkl + rowB * 128 + 64 + sg * 8, &Bl[rb * 64]);
  }
  __syncthreads();

  f32x4 acc[4][4];
#pragma unroll
  for (int m = 0; m < 4; ++m)
#pragma unroll
    for (int n = 0; n < 4; ++n) acc[m][n] = (f32x4){0.f, 0.f, 0.f, 0.f};

#pragma unroll
  for (int ks = 0; ks < 2; ++ks) {
    bf16x8 ah[4], al4[4], bh[4], bl4[4];
#pragma unroll
    for (int m = 0; m < 4; ++m) {
      int row = wr * 64 + m * 16 + (l & 15);
      int off = row * 64 + ((ks * 4 + (l >> 4)) ^ (row & 7)) * 8;
      ah[m] = *reinterpret_cast<const bf16x8*>(&Ah[off]);
      al4[m] = *reinterpret_cast<const bf16x8*>(&Al[off]);
    }
#pragma unroll
    for (int n = 0; n < 4; ++n) {
      int row = wc * 64 + n * 16 + (l & 15);
      int off = row * 64 + ((ks * 4 + (l >> 4)) ^ (row & 7)) * 8;
      bh[n] = *reinterpret_cast<const bf16x8*>(&Bh[off]);
      bl4[n] = *reinterpret_cast<const bf16x8*>(&Bl[off]);
    }
#pragma unroll
    for (int m = 0; m < 4; ++m)
#pragma unroll
      for (int n = 0; n < 4; ++n) {
        acc[m][n] = MFMA16(ah[m], bh[n], acc[m][n]);
        acc[m][n] = MFMA16(ah[m], bl4[n], acc[m][n]);
        acc[m][n] = MFMA16(al4[m], bh[n], acc[m][n]);
      }
  }

  unsigned short* sb = st + (long)b * 512 * 512;
#pragma unroll
  for (int m = 0; m < 4; ++m)
#pragma unroll
    for (int n = 0; n < 4; ++n) {
      int i0 = iBase + wr * 64 + m * 16 + (l >> 4) * 4;
      int j = jBase + wc * 64 + n * 16 + (l & 15);
      unsigned short p[4];
#pragma unroll
      for (int reg = 0; reg < 4; ++reg) {
        float sg2 = 1.0f / (1.0f + __expf(-acc[m][n][reg]));
        p[reg] = f2bf(__expf(sg2));
      }
      *reinterpret_cast<uint2*>(&sb[(long)j * 512 + i0]) = *reinterpret_cast<uint2*>(p);
    }
}

// -------- K2b: per-row (j) sums of st -> rsum = 1/sum, attbias = (st.bias)/sum ----
__global__ __launch_bounds__(256) void k2b_rsum(const unsigned short* __restrict__ st,
                                                const float* __restrict__ bias,
                                                float* __restrict__ rsum,
                                                float* __restrict__ attbias) {
  int jg = blockIdx.x * 4 + (threadIdx.x >> 6);
  int l = threadIdx.x & 63;
  const unsigned short* row = st + (long)jg * 512 + l * 8;
  ushort4 u0 = *reinterpret_cast<const ushort4*>(row);
  ushort4 u1 = *reinterpret_cast<const ushort4*>(row + 4);
  float4 b0 = *reinterpret_cast<const float4*>(&bias[l * 8]);
  float4 b1 = *reinterpret_cast<const float4*>(&bias[l * 8 + 4]);
  float f0 = bf2f(u0.x), f1 = bf2f(u0.y), f2 = bf2f(u0.z), f3 = bf2f(u0.w);
  float f4 = bf2f(u1.x), f5 = bf2f(u1.y), f6 = bf2f(u1.z), f7 = bf2f(u1.w);
  float sum = (f0 + f1) + (f2 + f3) + ((f4 + f5) + (f6 + f7));
  float sumb = f0 * b0.x + f1 * b0.y + f2 * b0.z + f3 * b0.w +
               f4 * b1.x + f5 * b1.y + f6 * b1.z + f7 * b1.w;
#pragma unroll
  for (int off = 32; off > 0; off >>= 1) {
    sum += __shfl_down(sum, off);
    sumb += __shfl_down(sumb, off);
  }
  if (l == 0) {
    float r = 1.0f / sum;
    rsum[jg] = r;
    attbias[jg] = sumb * r;
  }
}

// -------- transpose + fp32->bf16 convert: out[c][r] = bf16(in[r][c]) --------
__global__ __launch_bounds__(256) void transpose_conv(const float* __restrict__ in,
                                                      unsigned short* __restrict__ out,
                                                      int inRows, int inCols,
                                                      long inBatch, long outBatch) {
  __shared__ unsigned short lt[64][65];
  int b = blockIdx.z;
  int r0 = blockIdx.y * 64;
  int c0 = blockIdx.x * 64;
  const float* I = in + (long)b * inBatch;
  unsigned short* O = out + (long)b * outBatch;
  int t = threadIdx.x;
  int cl = (t & 15) * 4;
  int rl = t >> 4;
#pragma unroll
  for (int rr = 0; rr < 4; ++rr) {
    int r = rl + rr * 16;
    float4 v = *reinterpret_cast<const float4*>(&I[(long)(r0 + r) * inCols + c0 + cl]);
    lt[cl + 0][r] = f2bf(v.x);
    lt[cl + 1][r] = f2bf(v.y);
    lt[cl + 2][r] = f2bf(v.z);
    lt[cl + 3][r] = f2bf(v.w);
  }
  __syncthreads();
#pragma unroll
  for (int rr = 0; rr < 4; ++rr) {
    int c = rl + rr * 16;
    unsigned short v[4] = {lt[c][cl], lt[c][cl + 1], lt[c][cl + 2], lt[c][cl + 3]};
    *reinterpret_cast<uint2*>(&O[(long)(c0 + c) * inRows + r0 + cl]) =
        *reinterpret_cast<uint2*>(&v[0]);
  }
}

// ======== 256x256 bf16 MFMA GEMM, BK=64, 8 waves, 8-PHASE schedule (m201) ========
template <int MODE>
__global__ __launch_bounds__(512) void mfma_nt256(const unsigned short* __restrict__ Abase,
                                                  const unsigned short* __restrict__ Bbase,
                                                  const float* __restrict__ rowscale,
                                                  unsigned short* __restrict__ Wout,
                                                  float* __restrict__ Fout) {
  __shared__ unsigned short As[2][256 * 64];
  __shared__ unsigned short Bs[2][256 * 64];
  const int t = threadIdx.x;
  const int l = t & 63;
  const int w = t >> 6;          // 0..7
  const int wr = w >> 2;         // 0..1  (M: 2 x 128)
  const int wc = w & 3;          // 0..3  (N: 4 x 64)

  const int cpx = gridDim.x >> 3;
  const int orig = blockIdx.x;
  const int lw = (orig & 7) * cpx + (orig >> 3);
  const int TPB_SH = (MODE == 0) ? 2 : 3;
  const int b = lw >> TPB_SH;
  const int tile = lw & ((1 << TPB_SH) - 1);
  const int mBase = (tile >> 1) * 256;
  const int nBase = (tile & 1) * 256;

  const unsigned short* Ag = Abase + ((MODE == 0) ? 0L : (long)b * (1024 * 512)) + (long)mBase * 512;
  const unsigned short* Bg = Bbase + (long)b * (512 * 512) + (long)nBase * 512;

  f32x4 acc[8][4];
#pragma unroll
  for (int m = 0; m < 8; ++m)
#pragma unroll
    for (int n = 0; n < 4; ++n) acc[m][n] = (f32x4){0.f, 0.f, 0.f, 0.f};

  const int srcslot = (l & 7) ^ (l >> 3);
  const int so0 = ((l >> 4) ^ (l & 7)) * 8;
  const int so1 = ((4 + (l >> 4)) ^ (l & 7)) * 8;

#define STG_A(p, tt, pr)                                                       \
  gld_lds16(Ag + (long)((pr) * 64 + w * 8 + (l >> 3)) * 512 + (tt) * 64 + srcslot * 8, \
            &As[p][((pr) * 64 + w * 8) * 64]);
#define STG_B(p, tt, pr)                                                       \
  gld_lds16(Bg + (long)((pr) * 64 + w * 8 + (l >> 3)) * 512 + (tt) * 64 + srcslot * 8, \
            &Bs[p][((pr) * 64 + w * 8) * 64]);

#define PHASE(p, q, STAGE_STMT, VMSTMT)                                        \
  {                                                                            \
    bf16x8 a00 = *reinterpret_cast<const bf16x8*>(                             \
        &As[p][(wr * 128 + (2 * (q)) * 16 + (l & 15)) * 64 + so0]);            \
    bf16x8 a01 = *reinterpret_cast<const bf16x8*>(                             \
        &As[p][(wr * 128 + (2 * (q)) * 16 + (l & 15)) * 64 + so1]);            \
    bf16x8 a10 = *reinterpret_cast<const bf16x8*>(                             \
        &As[p][(wr * 128 + (2 * (q) + 1) * 16 + (l & 15)) * 64 + so0]);        \
    bf16x8 a11 = *reinterpret_cast<const bf16x8*>(                             \
        &As[p][(wr * 128 + (2 * (q) + 1) * 16 + (l & 15)) * 64 + so1]);        \
    if ((q) == 0) {                                                            \
      _Pragma("unroll") for (int n = 0; n < 4; ++n) {                          \
        bfr0[n] = *reinterpret_cast<const bf16x8*>(                            \
            &Bs[p][(wc * 64 + n * 16 + (l & 15)) * 64 + so0]);                 \
        bfr1[n] = *reinterpret_cast<const bf16x8*>(                            \
            &Bs[p][(wc * 64 + n * 16 + (l & 15)) * 64 + so1]);                 \
      }                                                                        \
    }                                                                          \
    STAGE_STMT;                                                                \
    SCHED0();                                                                  \
    __builtin_amdgcn_s_barrier();                                              \
    LGKM0();                                                                   \
    __builtin_amdgcn_s_setprio(1);                                             \
    _Pragma("unroll") for (int n = 0; n < 4; ++n) {                            \
      acc[2 * (q)][n] = MFMA16(a00, bfr0[n], acc[2 * (q)][n]);                 \
      acc[2 * (q)][n] = MFMA16(a01, bfr1[n], acc[2 * (q)][n]);                 \
      acc[2 * (q) + 1][n] = MFMA16(a10, bfr0[n], acc[2 * (q) + 1][n]);         \
      acc[2 * (q) + 1][n] = MFMA16(a11, bfr1[n], acc[2 * (q) + 1][n]);         \
    }                                                                          \
    __builtin_amdgcn_s_setprio(0);                                             \
    VMSTMT;                                                                    \
    NTBAR();                                                                   \
  }

  bf16x8 bfr0[4], bfr1[4];

  // prologue: buf0 <- tile0 (8 loads), buf1 <- B0,B1,Ha of tile1 (6 loads)
  STG_A(0, 0, 0); STG_A(0, 0, 1); STG_A(0, 0, 2); STG_A(0, 0, 3);
  STG_B(0, 0, 0); STG_B(0, 0, 1); STG_B(0, 0, 2); STG_B(0, 0, 3);
  STG_B(1, 1, 0); STG_B(1, 1, 1); STG_B(1, 1, 2); STG_B(1, 1, 3);
  STG_A(1, 1, 0); STG_A(1, 1, 2);
  VMW(6);
  NTBAR();

  for (int it = 0; it < 4; ++it) {
    const int t1 = 2 * it + 1;
    const int t2 = (2 * it + 2 < 8) ? 2 * it + 2 : 7;
    const int t3 = (2 * it + 3 < 8) ? 2 * it + 3 : 7;
    PHASE(0, 0, { STG_A(1, t1, 1); STG_A(1, t1, 3); }, );
    PHASE(0, 1, { STG_B(0, t2, 0); STG_B(0, t2, 1); }, VMW(10));
    PHASE(0, 2, { STG_B(0, t2, 2); STG_B(0, t2, 3); }, );
    PHASE(0, 3, { STG_A(0, t2, 0); STG_A(0, t2, 2); }, VMW(8));
    PHASE(1, 0, { STG_A(0, t2, 1); STG_A(0, t2, 3); }, );
    PHASE(1, 1, { STG_B(1, t3, 0); STG_B(1, t3, 1); }, VMW(10));
    PHASE(1, 2, { STG_B(1, t3, 2); STG_B(1, t3, 3); }, );
    PHASE(1, 3, { STG_A(1, t3, 0); STG_A(1, t3, 2); }, VMW(8));
  }
#undef PHASE
#undef STG_A
#undef STG_B

  if (MODE == 0) {
    unsigned short* W = Wout + (long)b * (512 * 512);
#pragma unroll
    for (int n = 0; n < 4; ++n) {
      int j = nBase + wc * 64 + n * 16 + (l & 15);
      float rs = rowscale[b * 512 + j];
#pragma unroll
      for (int m = 0; m < 8; ++m) {
        int c0 = mBase + wr * 128 + m * 16 + (l >> 4) * 4;
        unsigned short p[4];
#pragma unroll
        for (int reg = 0; reg < 4; ++reg) p[reg] = f2bf(acc[m][n][reg] * rs);
        *reinterpret_cast<uint2*>(&W[(long)j * 512 + c0]) = *reinterpret_cast<uint2*>(p);
      }
    }
  } else {
    float* O = Fout + (long)b * (512 * 1024);
#pragma unroll
    for (int n = 0; n < 4; ++n) {
      int j = nBase + wc * 64 + n * 16 + (l & 15);
      float ab = rowscale[b * 512 + j];
#pragma unroll
      for (int m = 0; m < 8; ++m) {
        int n0 = mBase + wr * 128 + m * 16 + (l >> 4) * 4;
        *reinterpret_cast<float4*>(&O[(long)j * 1024 + n0]) =
            make_float4(acc[m][n][0] + ab, acc[m][n][1] + ab,
                        acc[m][n][2] + ab, acc[m][n][3] + ab);
      }
    }
  }
}

extern "C" void kernel_launch(void* const* d_in, const int* in_sizes, int n_in,
                              void* d_out, int out_size, void* d_ws, size_t ws_size,
                              hipStream_t stream) {
  const float* x  = (const float*)d_in[0];
  const float* Qm = (const float*)d_in[1];
  const float* Km = (const float*)d_in[2];
  const float* vw = (const float*)d_in[3];
  const float* vb = (const float*)d_in[4];
  float* out = (float*)d_out;

  float* ws = (float*)d_ws;
  unsigned short* qkh  = (unsigned short*)ws;                         // 4,194,304 ush
  unsigned short* qkl  = qkh + 4194304;                               // 4,194,304 ush
  unsigned short* st   = (unsigned short*)(ws + 4194304);             // spans 8,388,608 f
  unsigned short* weff = (unsigned short*)(ws + 4194304 + 8388608);   // spans 8,388,608 f
  unsigned short* xbT  = (unsigned short*)(ws + 4194304 + 16777216);  // spans 16,777,216 f
  unsigned short* vwT  = (unsigned short*)(ws + 4194304 + 33554432);  // spans 131,072 f
  unsigned short* qkTh = (unsigned short*)(ws + 4194304 + 33554432 + 131072);  // 65,536 f
  unsigned short* qkTl = qkTh + 131072;                               // 65,536 f
  float* rsum    = ws + 4194304 + 33554432 + 131072 + 131072;         // 32,768 f
  float* attbias = rsum + 32768;                                      // 32,768 f

  // T2: vwT[c][i] = bf16(vw[i][c])
  transpose_conv<<<dim3(8, 8, 1), 256, 0, stream>>>(vw, vwT, 512, 512, 0L, 0L);
  // T3: split-transposed [Qm|Km] -> qkTh/qkTl [128][1024]
  qkm_split<<<dim3(16, 2), 256, 0, stream>>>(Qm, Km, qkTh, qkTl);
  // K1: qkh/qkl = split(x @ [Qm|Km]) + fused xbT transpose (barrier-free, 2048 waves)
  k1_mfma<<<512, 256, 0, stream>>>(x, qkTh, qkTl, qkh, qkl, xbT);
  // K2a: st[b,j,i] = exp(sigmoid(q_i . k_j)), gld_lds staging of qkh/qkl
  k2a_mfma<<<1024, 256, 0, stream>>>(qkh, qkl, st);
  // K2b: rsum, attbias
  k2b_rsum<<<8192, 256, 0, stream>>>(st, vb, rsum, attbias);
  // K3: weff = diag(rsum) . st . Vw   (A=vwT, B=st), 4 tiles/b
  mfma_nt256<0><<<256, 512, 0, stream>>>(vwT, st, rsum, weff, nullptr);
  // K4: out = weff . xf + attbias     (A=xbT, B=weff), 8 tiles/b
  mfma_nt256<1><<<512, 512, 0, stream>>>(xbT, weff, attbias, nullptr, out);
}

// Round 14
// 204.589 us; speedup vs baseline: 1.1923x; 1.1710x over previous
//
#include <hip/hip_runtime.h>

typedef __attribute__((ext_vector_type(8))) short bf16x8;
typedef __attribute__((ext_vector_type(4))) float f32x4;

__device__ __forceinline__ unsigned short f2bf(float f) {
  unsigned u = __builtin_bit_cast(unsigned, f);
  unsigned r = (u + 0x7FFFu + ((u >> 16) & 1u)) >> 16;
  return (unsigned short)r;
}
__device__ __forceinline__ float bf2f(unsigned short h) {
  return __builtin_bit_cast(float, (unsigned)h << 16);
}
__device__ __forceinline__ unsigned pack2(unsigned short a, unsigned short b) {
  return (unsigned)a | ((unsigned)b << 16);
}

__device__ __forceinline__ void gld_lds16(const void* g, void* l) {
  __builtin_amdgcn_global_load_lds(
      (const __attribute__((address_space(1))) unsigned int*)g,
      (__attribute__((address_space(3))) unsigned int*)l, 16, 0, 0);
}

#define SCHED0() __builtin_amdgcn_sched_barrier(0)
#define NTBAR() do { SCHED0(); __builtin_amdgcn_s_barrier(); SCHED0(); } while (0)
#define VMW(N) do { asm volatile("s_waitcnt vmcnt(" #N ")" ::: "memory"); SCHED0(); } while (0)
#define LGKM0() do { asm volatile("s_waitcnt lgkmcnt(0)" ::: "memory"); SCHED0(); } while (0)
#define MFMA16(a, b, c) __builtin_amdgcn_mfma_f32_16x16x32_bf16(a, b, c, 0, 0, 0)

// split 8 fp32 -> hi/lo bf16, store as uint4 pair (ds_write_b128)
__device__ __forceinline__ void split8_store(float4 v0, float4 v1,
                                             unsigned short* Hdst,
                                             unsigned short* Ldst) {
  float f[8] = {v0.x, v0.y, v0.z, v0.w, v1.x, v1.y, v1.z, v1.w};
  unsigned short hh[8], ll[8];
#pragma unroll
  for (int i = 0; i < 8; ++i) {
    hh[i] = f2bf(f[i]);
    ll[i] = f2bf(f[i] - bf2f(hh[i]));
  }
  *reinterpret_cast<uint4*>(Hdst) = make_uint4(pack2(hh[0], hh[1]), pack2(hh[2], hh[3]),
                                               pack2(hh[4], hh[5]), pack2(hh[6], hh[7]));
  *reinterpret_cast<uint4*>(Ldst) = make_uint4(pack2(ll[0], ll[1]), pack2(ll[2], ll[3]),
                                               pack2(ll[4], ll[5]), pack2(ll[6], ll[7]));
}

// -------- QB prep: Th/Tl[d][k] = split-bf16 of [Qm | Km] column d --------
__global__ __launch_bounds__(256) void qkm_split(const float* __restrict__ Qm,
                                                 const float* __restrict__ Km,
                                                 unsigned short* __restrict__ Th,
                                                 unsigned short* __restrict__ Tl) {
  __shared__ float lt[64][65];
  int k0 = blockIdx.x * 64;
  int half = blockIdx.y;
  const float* M = half ? Km : Qm;
  int t = threadIdx.x;
  int cl = (t & 15) * 4;
  int rl = t >> 4;
#pragma unroll
  for (int rr = 0; rr < 4; ++rr) {
    int r = rl + rr * 16;
    float4 v = *reinterpret_cast<const float4*>(&M[(long)(k0 + r) * 64 + cl]);
    lt[cl + 0][r] = v.x;
    lt[cl + 1][r] = v.y;
    lt[cl + 2][r] = v.z;
    lt[cl + 3][r] = v.w;
  }
  __syncthreads();
#pragma unroll
  for (int rr = 0; rr < 4; ++rr) {
    int c = rl + rr * 16;
    unsigned short h[4], lo[4];
#pragma unroll
    for (int i = 0; i < 4; ++i) {
      float f = lt[c][cl + i];
      h[i] = f2bf(f);
      lo[i] = f2bf(f - bf2f(h[i]));
    }
    *reinterpret_cast<uint2*>(&Th[(long)(half * 64 + c) * 1024 + k0 + cl]) =
        make_uint2(pack2(h[0], h[1]), pack2(h[2], h[3]));
    *reinterpret_cast<uint2*>(&Tl[(long)(half * 64 + c) * 1024 + k0 + cl]) =
        make_uint2(pack2(lo[0], lo[1]), pack2(lo[2], lo[3]));
  }
}

// -------- K1: qkh/qkl = split(x @ [Qm|Km]), counted-vmcnt pipeline (UNFUSED) ----
// Per K-tile (BK=32), vmem issue order: x-load t+2 (2) | BAR | gld_lds D(t+2) (4)
// | VMW(6) | BAR.  VMW(6) == "previous iteration's 6 ops done": D(t+1) landed.
__global__ __launch_bounds__(256) void k1_mfma(const float* __restrict__ x,
                                               const unsigned short* __restrict__ Th,
                                               const unsigned short* __restrict__ Tl,
                                               unsigned short* __restrict__ qkh,
                                               unsigned short* __restrict__ qkl) {
  __shared__ unsigned short Dh[2][128 * 32];
  __shared__ unsigned short Dl[2][128 * 32];
  __shared__ unsigned short Xh[2][64 * 32];
  __shared__ unsigned short Xl[2][64 * 32];
  const int t = threadIdx.x;
  const int l = t & 63;
  const int w = t >> 6;
  const int wr = w >> 1, wc = w & 1;
  const long mBase = (long)blockIdx.x * 64;

  f32x4 acc[4][2];
#pragma unroll
  for (int m = 0; m < 4; ++m)
#pragma unroll
    for (int n = 0; n < 2; ++n) acc[m][n] = (f32x4){0.f, 0.f, 0.f, 0.f};

  const int xrow_l = t >> 2;
  const int kslot = t & 3;
  const int xsl = kslot ^ ((t >> 3) & 3);
  const int srcslot = (l & 3) ^ ((l >> 3) & 3);
  const int frag_off = (l & 15) * 32 + ((((l >> 4) ^ (l >> 1)) & 3) * 8);
  const float* xrow = x + (mBase + xrow_l) * 1024;

#define K1_LOADX(r0, r1, tt)                                                  \
  {                                                                           \
    r0 = *reinterpret_cast<const float4*>(&xrow[(tt) * 32 + kslot * 8]);      \
    r1 = *reinterpret_cast<const float4*>(&xrow[(tt) * 32 + kslot * 8 + 4]);  \
  }

#define K1_STAGE_D(tt, p)                                                     \
  {                                                                           \
    _Pragma("unroll") for (int c = 0; c < 2; ++c) {                           \
      int ch = c * 4 + w;                                                     \
      int row = ch * 16 + (l >> 2);                                           \
      gld_lds16(Th + (long)row * 1024 + (tt) * 32 + srcslot * 8, &Dh[p][ch * 512]); \
      gld_lds16(Tl + (long)row * 1024 + (tt) * 32 + srcslot * 8, &Dl[p][ch * 512]); \
    }                                                                         \
  }

#define K1_COMPUTE(p)                                                         \
  {                                                                           \
    bf16x8 dh[4], dl[4], xh[2], xl[2];                                        \
    _Pragma("unroll") for (int m = 0; m < 4; ++m) {                           \
      dh[m] = *reinterpret_cast<const bf16x8*>(&Dh[p][(wr * 64 + m * 16) * 32 + frag_off]); \
      dl[m] = *reinterpret_cast<const bf16x8*>(&Dl[p][(wr * 64 + m * 16) * 32 + frag_off]); \
    }                                                                         \
    _Pragma("unroll") for (int n = 0; n < 2; ++n) {                           \
      xh[n] = *reinterpret_cast<const bf16x8*>(&Xh[p][(wc * 32 + n * 16) * 32 + frag_off]); \
      xl[n] = *reinterpret_cast<const bf16x8*>(&Xl[p][(wc * 32 + n * 16) * 32 + frag_off]); \
    }                                                                         \
    _Pragma("unroll") for (int m = 0; m < 4; ++m)                             \
        _Pragma("unroll") for (int n = 0; n < 2; ++n) {                       \
      acc[m][n] = MFMA16(dh[m], xh[n], acc[m][n]);                            \
      acc[m][n] = MFMA16(dh[m], xl[n], acc[m][n]);                            \
      acc[m][n] = MFMA16(dl[m], xh[n], acc[m][n]);                            \
    }                                                                         \
  }

  float4 xa0, xa1, xb0, xb1;

  // prologue: x(0)(2), D(0)(4), x(1)(2), split x(0)->buf0, D(1)(4), VMW(6)
  K1_LOADX(xa0, xa1, 0);
  K1_STAGE_D(0, 0);
  K1_LOADX(xb0, xb1, 1);
  split8_store(xa0, xa1, &Xh[0][xrow_l * 32 + xsl * 8], &Xl[0][xrow_l * 32 + xsl * 8]);
  K1_STAGE_D(1, 1);
  VMW(6);
  LGKM0();
  NTBAR();

  for (int kt = 0; kt < 32; kt += 2) {
    // even body: tile kt, p=0; split(x(kt+1)) -> buf1; load x(kt+2)
    {
      const int tn = (kt + 2 < 32) ? kt + 2 : 31;
      K1_COMPUTE(0);
      K1_LOADX(xa0, xa1, tn);
      split8_store(xb0, xb1, &Xh[1][xrow_l * 32 + xsl * 8], &Xl[1][xrow_l * 32 + xsl * 8]);
      LGKM0();
      NTBAR();
      K1_STAGE_D(tn, 0);
      VMW(6);
      NTBAR();
    }
    // odd body: tile kt+1, p=1; split(x(kt+2)) -> buf0; load x(kt+3)
    {
      const int tn = (kt + 3 < 32) ? kt + 3 : 31;
      K1_COMPUTE(1);
      K1_LOADX(xb0, xb1, tn);
      split8_store(xa0, xa1, &Xh[0][xrow_l * 32 + xsl * 8], &Xl[0][xrow_l * 32 + xsl * 8]);
      LGKM0();
      NTBAR();
      K1_STAGE_D(tn, 1);
      VMW(6);
      NTBAR();
    }
  }

  // epilogue: split acc -> qkh/qkl
#pragma unroll
  for (int m = 0; m < 4; ++m)
#pragma unroll
    for (int n = 0; n < 2; ++n) {
      int d0 = wr * 64 + m * 16 + (l >> 4) * 4;
      long xr = mBase + wc * 32 + n * 16 + (l & 15);
      unsigned short h4[4], l4[4];
#pragma unroll
      for (int reg = 0; reg < 4; ++reg) {
        float v = acc[m][n][reg];
        h4[reg] = f2bf(v);
        l4[reg] = f2bf(v - bf2f(h4[reg]));
      }
      *reinterpret_cast<uint2*>(&qkh[xr * 128 + d0]) =
          make_uint2(pack2(h4[0], h4[1]), pack2(h4[2], h4[3]));
      *reinterpret_cast<uint2*>(&qkl[xr * 128 + d0]) =
          make_uint2(pack2(l4[0], l4[1]), pack2(l4[2], l4[3]));
    }
#undef K1_LOADX
#undef K1_STAGE_D
#undef K1_COMPUTE
}

// -------- K2a: st[b,j,i] = exp(sigmoid(q_i . k_j)), split-bf16 MFMA -----------
// Stages pre-split qkh/qkl via global_load_lds (lane-linear dest, swizzled src).
__global__ __launch_bounds__(256) void k2a_mfma(const unsigned short* __restrict__ qkh,
                                                const unsigned short* __restrict__ qkl,
                                                unsigned short* __restrict__ st) {
  __shared__ unsigned short Ah[128 * 64];
  __shared__ unsigned short Al[128 * 64];
  __shared__ unsigned short Bh[128 * 64];
  __shared__ unsigned short Bl[128 * 64];
  const int t = threadIdx.x;
  const int l = t & 63;
  const int w = t >> 6;
  const int wr = w >> 1, wc = w & 1;

  const int cpx = gridDim.x >> 3;
  const int orig = blockIdx.x;
  const int lw = (orig & 7) * cpx + (orig >> 3);
  const int b = lw >> 4;
  const int tile = lw & 15;
  const int iBase = (tile >> 2) * 128;
  const int jBase = (tile & 3) * 128;
  const long bq = (long)b * 512;

  const int sg = (l & 7) ^ (l >> 3);
#pragma unroll
  for (int c4 = 0; c4 < 4; ++c4) {
    int rb = w * 32 + c4 * 8;
    long rowA = bq + iBase + rb + (l >> 3);
    long rowB = bq + jBase + rb + (l >> 3);
    gld_lds16(qkh + rowA * 128 + sg * 8, &Ah[rb * 64]);
    gld_lds16(qkl + rowA * 128 + sg * 8, &Al[rb * 64]);
    gld_lds16(qkh + rowB * 128 + 64 + sg * 8, &Bh[rb * 64]);
    gld_lds16(qkl + rowB * 128 + 64 + sg * 8, &Bl[rb * 64]);
  }
  __syncthreads();

  f32x4 acc[4][4];
#pragma unroll
  for (int m = 0; m < 4; ++m)
#pragma unroll
    for (int n = 0; n < 4; ++n) acc[m][n] = (f32x4){0.f, 0.f, 0.f, 0.f};

#pragma unroll
  for (int ks = 0; ks < 2; ++ks) {
    bf16x8 ah[4], al4[4], bh[4], bl4[4];
#pragma unroll
    for (int m = 0; m < 4; ++m) {
      int row = wr * 64 + m * 16 + (l & 15);
      int off = row * 64 + ((ks * 4 + (l >> 4)) ^ (row & 7)) * 8;
      ah[m] = *reinterpret_cast<const bf16x8*>(&Ah[off]);
      al4[m] = *reinterpret_cast<const bf16x8*>(&Al[off]);
    }
#pragma unroll
    for (int n = 0; n < 4; ++n) {
      int row = wc * 64 + n * 16 + (l & 15);
      int off = row * 64 + ((ks * 4 + (l >> 4)) ^ (row & 7)) * 8;
      bh[n] = *reinterpret_cast<const bf16x8*>(&Bh[off]);
      bl4[n] = *reinterpret_cast<const bf16x8*>(&Bl[off]);
    }
#pragma unroll
    for (int m = 0; m < 4; ++m)
#pragma unroll
      for (int n = 0; n < 4; ++n) {
        acc[m][n] = MFMA16(ah[m], bh[n], acc[m][n]);
        acc[m][n] = MFMA16(ah[m], bl4[n], acc[m][n]);
        acc[m][n] = MFMA16(al4[m], bh[n], acc[m][n]);
      }
  }

  unsigned short* sb = st + (long)b * 512 * 512;
#pragma unroll
  for (int m = 0; m < 4; ++m)
#pragma unroll
    for (int n = 0; n < 4; ++n) {
      int i0 = iBase + wr * 64 + m * 16 + (l >> 4) * 4;
      int j = jBase + wc * 64 + n * 16 + (l & 15);
      unsigned short p[4];
#pragma unroll
      for (int reg = 0; reg < 4; ++reg) {
        float sg2 = 1.0f / (1.0f + __expf(-acc[m][n][reg]));
        p[reg] = f2bf(__expf(sg2));
      }
      *reinterpret_cast<uint2*>(&sb[(long)j * 512 + i0]) = *reinterpret_cast<uint2*>(p);
    }
}

// -------- K2b: per-row (j) sums of st -> rsum = 1/sum, attbias = (st.bias)/sum ----
__global__ __launch_bounds__(256) void k2b_rsum(const unsigned short* __restrict__ st,
                                                const float* __restrict__ bias,
                                                float* __restrict__ rsum,
                                                float* __restrict__ attbias) {
  int jg = blockIdx.x * 4 + (threadIdx.x >> 6);
  int l = threadIdx.x & 63;
  const unsigned short* row = st + (long)jg * 512 + l * 8;
  ushort4 u0 = *reinterpret_cast<const ushort4*>(row);
  ushort4 u1 = *reinterpret_cast<const ushort4*>(row + 4);
  float4 b0 = *reinterpret_cast<const float4*>(&bias[l * 8]);
  float4 b1 = *reinterpret_cast<const float4*>(&bias[l * 8 + 4]);
  float f0 = bf2f(u0.x), f1 = bf2f(u0.y), f2 = bf2f(u0.z), f3 = bf2f(u0.w);
  float f4 = bf2f(u1.x), f5 = bf2f(u1.y), f6 = bf2f(u1.z), f7 = bf2f(u1.w);
  float sum = (f0 + f1) + (f2 + f3) + ((f4 + f5) + (f6 + f7));
  float sumb = f0 * b0.x + f1 * b0.y + f2 * b0.z + f3 * b0.w +
               f4 * b1.x + f5 * b1.y + f6 * b1.z + f7 * b1.w;
#pragma unroll
  for (int off = 32; off > 0; off >>= 1) {
    sum += __shfl_down(sum, off);
    sumb += __shfl_down(sumb, off);
  }
  if (l == 0) {
    float r = 1.0f / sum;
    rsum[jg] = r;
    attbias[jg] = sumb * r;
  }
}

// -------- transpose + fp32->bf16 convert: out[c][r] = bf16(in[r][c]) --------
__global__ __launch_bounds__(256) void transpose_conv(const float* __restrict__ in,
                                                      unsigned short* __restrict__ out,
                                                      int inRows, int inCols,
                                                      long inBatch, long outBatch) {
  __shared__ unsigned short lt[64][65];
  int b = blockIdx.z;
  int r0 = blockIdx.y * 64;
  int c0 = blockIdx.x * 64;
  const float* I = in + (long)b * inBatch;
  unsigned short* O = out + (long)b * outBatch;
  int t = threadIdx.x;
  int cl = (t & 15) * 4;
  int rl = t >> 4;
#pragma unroll
  for (int rr = 0; rr < 4; ++rr) {
    int r = rl + rr * 16;
    float4 v = *reinterpret_cast<const float4*>(&I[(long)(r0 + r) * inCols + c0 + cl]);
    lt[cl + 0][r] = f2bf(v.x);
    lt[cl + 1][r] = f2bf(v.y);
    lt[cl + 2][r] = f2bf(v.z);
    lt[cl + 3][r] = f2bf(v.w);
  }
  __syncthreads();
#pragma unroll
  for (int rr = 0; rr < 4; ++rr) {
    int c = rl + rr * 16;
    unsigned short v[4] = {lt[c][cl], lt[c][cl + 1], lt[c][cl + 2], lt[c][cl + 3]};
    *reinterpret_cast<uint2*>(&O[(long)(c0 + c) * inRows + r0 + cl]) =
        *reinterpret_cast<uint2*>(&v[0]);
  }
}

// ======== 256x256 bf16 MFMA GEMM, BK=64, 8 waves, 8-PHASE schedule (m201) ========
template <int MODE>
__global__ __launch_bounds__(512) void mfma_nt256(const unsigned short* __restrict__ Abase,
                                                  const unsigned short* __restrict__ Bbase,
                                                  const float* __restrict__ rowscale,
                                                  unsigned short* __restrict__ Wout,
                                                  float* __restrict__ Fout) {
  __shared__ unsigned short As[2][256 * 64];
  __shared__ unsigned short Bs[2][256 * 64];
  const int t = threadIdx.x;
  const int l = t & 63;
  const int w = t >> 6;          // 0..7
  const int wr = w >> 2;         // 0..1  (M: 2 x 128)
  const int wc = w & 3;          // 0..3  (N: 4 x 64)

  const int cpx = gridDim.x >> 3;
  const int orig = blockIdx.x;
  const int lw = (orig & 7) * cpx + (orig >> 3);
  const int TPB_SH = (MODE == 0) ? 2 : 3;
  const int b = lw >> TPB_SH;
  const int tile = lw & ((1 << TPB_SH) - 1);
  const int mBase = (tile >> 1) * 256;
  const int nBase = (tile & 1) * 256;

  const unsigned short* Ag = Abase + ((MODE == 0) ? 0L : (long)b * (1024 * 512)) + (long)mBase * 512;
  const unsigned short* Bg = Bbase + (long)b * (512 * 512) + (long)nBase * 512;

  f32x4 acc[8][4];
#pragma unroll
  for (int m = 0; m < 8; ++m)
#pragma unroll
    for (int n = 0; n < 4; ++n) acc[m][n] = (f32x4){0.f, 0.f, 0.f, 0.f};

  const int srcslot = (l & 7) ^ (l >> 3);
  const int so0 = ((l >> 4) ^ (l & 7)) * 8;
  const int so1 = ((4 + (l >> 4)) ^ (l & 7)) * 8;

#define STG_A(p, tt, pr)                                                       \
  gld_lds16(Ag + (long)((pr) * 64 + w * 8 + (l >> 3)) * 512 + (tt) * 64 + srcslot * 8, \
            &As[p][((pr) * 64 + w * 8) * 64]);
#define STG_B(p, tt, pr)                                                       \
  gld_lds16(Bg + (long)((pr) * 64 + w * 8 + (l >> 3)) * 512 + (tt) * 64 + srcslot * 8, \
            &Bs[p][((pr) * 64 + w * 8) * 64]);

#define PHASE(p, q, STAGE_STMT, VMSTMT)                                        \
  {                                                                            \
    bf16x8 a00 = *reinterpret_cast<const bf16x8*>(                             \
        &As[p][(wr * 128 + (2 * (q)) * 16 + (l & 15)) * 64 + so0]);            \
    bf16x8 a01 = *reinterpret_cast<const bf16x8*>(                             \
        &As[p][(wr * 128 + (2 * (q)) * 16 + (l & 15)) * 64 + so1]);            \
    bf16x8 a10 = *reinterpret_cast<const bf16x8*>(                             \
        &As[p][(wr * 128 + (2 * (q) + 1) * 16 + (l & 15)) * 64 + so0]);        \
    bf16x8 a11 = *reinterpret_cast<const bf16x8*>(                             \
        &As[p][(wr * 128 + (2 * (q) + 1) * 16 + (l & 15)) * 64 + so1]);        \
    if ((q) == 0) {                                                            \
      _Pragma("unroll") for (int n = 0; n < 4; ++n) {                          \
        bfr0[n] = *reinterpret_cast<const bf16x8*>(                            \
            &Bs[p][(wc * 64 + n * 16 + (l & 15)) * 64 + so0]);                 \
        bfr1[n] = *reinterpret_cast<const bf16x8*>(                            \
            &Bs[p][(wc * 64 + n * 16 + (l & 15)) * 64 + so1]);                 \
      }                                                                        \
    }                                                                          \
    STAGE_STMT;                                                                \
    SCHED0();                                                                  \
    __builtin_amdgcn_s_barrier();                                              \
    LGKM0();                                                                   \
    __builtin_amdgcn_s_setprio(1);                                             \
    _Pragma("unroll") for (int n = 0; n < 4; ++n) {                            \
      acc[2 * (q)][n] = MFMA16(a00, bfr0[n], acc[2 * (q)][n]);                 \
      acc[2 * (q)][n] = MFMA16(a01, bfr1[n], acc[2 * (q)][n]);                 \
      acc[2 * (q) + 1][n] = MFMA16(a10, bfr0[n], acc[2 * (q) + 1][n]);         \
      acc[2 * (q) + 1][n] = MFMA16(a11, bfr1[n], acc[2 * (q) + 1][n]);         \
    }                                                                          \
    __builtin_amdgcn_s_setprio(0);                                             \
    VMSTMT;                                                                    \
    NTBAR();                                                                   \
  }

  bf16x8 bfr0[4], bfr1[4];

  // prologue: buf0 <- tile0 (8 loads), buf1 <- B0,B1,Ha of tile1 (6 loads)
  STG_A(0, 0, 0); STG_A(0, 0, 1); STG_A(0, 0, 2); STG_A(0, 0, 3);
  STG_B(0, 0, 0); STG_B(0, 0, 1); STG_B(0, 0, 2); STG_B(0, 0, 3);
  STG_B(1, 1, 0); STG_B(1, 1, 1); STG_B(1, 1, 2); STG_B(1, 1, 3);
  STG_A(1, 1, 0); STG_A(1, 1, 2);
  VMW(6);
  NTBAR();

  for (int it = 0; it < 4; ++it) {
    const int t1 = 2 * it + 1;
    const int t2 = (2 * it + 2 < 8) ? 2 * it + 2 : 7;
    const int t3 = (2 * it + 3 < 8) ? 2 * it + 3 : 7;
    PHASE(0, 0, { STG_A(1, t1, 1); STG_A(1, t1, 3); }, );
    PHASE(0, 1, { STG_B(0, t2, 0); STG_B(0, t2, 1); }, VMW(10));
    PHASE(0, 2, { STG_B(0, t2, 2); STG_B(0, t2, 3); }, );
    PHASE(0, 3, { STG_A(0, t2, 0); STG_A(0, t2, 2); }, VMW(8));
    PHASE(1, 0, { STG_A(0, t2, 1); STG_A(0, t2, 3); }, );
    PHASE(1, 1, { STG_B(1, t3, 0); STG_B(1, t3, 1); }, VMW(10));
    PHASE(1, 2, { STG_B(1, t3, 2); STG_B(1, t3, 3); }, );
    PHASE(1, 3, { STG_A(1, t3, 0); STG_A(1, t3, 2); }, VMW(8));
  }
#undef PHASE
#undef STG_A
#undef STG_B

  if (MODE == 0) {
    unsigned short* W = Wout + (long)b * (512 * 512);
#pragma unroll
    for (int n = 0; n < 4; ++n) {
      int j = nBase + wc * 64 + n * 16 + (l & 15);
      float rs = rowscale[b * 512 + j];
#pragma unroll
      for (int m = 0; m < 8; ++m) {
        int c0 = mBase + wr * 128 + m * 16 + (l >> 4) * 4;
        unsigned short p[4];
#pragma unroll
        for (int reg = 0; reg < 4; ++reg) p[reg] = f2bf(acc[m][n][reg] * rs);
        *reinterpret_cast<uint2*>(&W[(long)j * 512 + c0]) = *reinterpret_cast<uint2*>(p);
      }
    }
  } else {
    float* O = Fout + (long)b * (512 * 1024);
#pragma unroll
    for (int n = 0; n < 4; ++n) {
      int j = nBase + wc * 64 + n * 16 + (l & 15);
      float ab = rowscale[b * 512 + j];
#pragma unroll
      for (int m = 0; m < 8; ++m) {
        int n0 = mBase + wr * 128 + m * 16 + (l >> 4) * 4;
        *reinterpret_cast<float4*>(&O[(long)j * 1024 + n0]) =
            make_float4(acc[m][n][0] + ab, acc[m][n][1] + ab,
                        acc[m][n][2] + ab, acc[m][n][3] + ab);
      }
    }
  }
}

extern "C" void kernel_launch(void* const* d_in, const int* in_sizes, int n_in,
                              void* d_out, int out_size, void* d_ws, size_t ws_size,
                              hipStream_t stream) {
  const float* x  = (const float*)d_in[0];
  const float* Qm = (const float*)d_in[1];
  const float* Km = (const float*)d_in[2];
  const float* vw = (const float*)d_in[3];
  const float* vb = (const float*)d_in[4];
  float* out = (float*)d_out;

  float* ws = (float*)d_ws;
  unsigned short* qkh  = (unsigned short*)ws;                         // 4,194,304 ush
  unsigned short* qkl  = qkh + 4194304;                               // 4,194,304 ush
  unsigned short* st   = (unsigned short*)(ws + 4194304);             // spans 8,388,608 f
  unsigned short* weff = (unsigned short*)(ws + 4194304 + 8388608);   // spans 8,388,608 f
  unsigned short* xbT  = (unsigned short*)(ws + 4194304 + 16777216);  // spans 16,777,216 f
  unsigned short* vwT  = (unsigned short*)(ws + 4194304 + 33554432);  // spans 131,072 f
  unsigned short* qkTh = (unsigned short*)(ws + 4194304 + 33554432 + 131072);  // 65,536 f
  unsigned short* qkTl = qkTh + 131072;                               // 65,536 f
  float* rsum    = ws + 4194304 + 33554432 + 131072 + 131072;         // 32,768 f
  float* attbias = rsum + 32768;                                      // 32,768 f

  // T1: xbT[b][n][c] = bf16(x[b][c][n])  (standalone transpose, unfused)
  transpose_conv<<<dim3(16, 8, 64), 256, 0, stream>>>(x, xbT, 512, 1024, 524288L, 524288L);
  // T2: vwT[c][i] = bf16(vw[i][c])
  transpose_conv<<<dim3(8, 8, 1), 256, 0, stream>>>(vw, vwT, 512, 512, 0L, 0L);
  // T3: split-transposed [Qm|Km] -> qkTh/qkTl [128][1024]
  qkm_split<<<dim3(16, 2), 256, 0, stream>>>(Qm, Km, qkTh, qkTl);
  // K1: qkh/qkl = split(x @ [Qm|Km]), counted-vmcnt pipeline, no fusion
  k1_mfma<<<512, 256, 0, stream>>>(x, qkTh, qkTl, qkh, qkl);
  // K2a: st[b,j,i] = exp(sigmoid(q_i . k_j)), gld_lds staging of qkh/qkl
  k2a_mfma<<<1024, 256, 0, stream>>>(qkh, qkl, st);
  // K2b: rsum, attbias
  k2b_rsum<<<8192, 256, 0, stream>>>(st, vb, rsum, attbias);
  // K3: weff = diag(rsum) . st . Vw   (A=vwT, B=st), 4 tiles/b
  mfma_nt256<0><<<256, 512, 0, stream>>>(vwT, st, rsum, weff, nullptr);
  // K4: out = weff . xf + attbias     (A=xbT, B=weff), 8 tiles/b
  mfma_nt256<1><<<512, 512, 0, stream>>>(xbT, weff, attbias, nullptr, out);
}

// Round 15
// 190.808 us; speedup vs baseline: 1.2784x; 1.0722x over previous
//
#include <hip/hip_runtime.h>

typedef __attribute__((ext_vector_type(8))) short bf16x8;
typedef __attribute__((ext_vector_type(4))) float f32x4;

__device__ __forceinline__ unsigned short f2bf(float f) {
  unsigned u = __builtin_bit_cast(unsigned, f);
  unsigned r = (u + 0x7FFFu + ((u >> 16) & 1u)) >> 16;
  return (unsigned short)r;
}
__device__ __forceinline__ float bf2f(unsigned short h) {
  return __builtin_bit_cast(float, (unsigned)h << 16);
}
__device__ __forceinline__ unsigned pack2(unsigned short a, unsigned short b) {
  return (unsigned)a | ((unsigned)b << 16);
}

__device__ __forceinline__ void gld_lds16(const void* g, void* l) {
  __builtin_amdgcn_global_load_lds(
      (const __attribute__((address_space(1))) unsigned int*)g,
      (__attribute__((address_space(3))) unsigned int*)l, 16, 0, 0);
}

#define SCHED0() __builtin_amdgcn_sched_barrier(0)
#define NTBAR() do { SCHED0(); __builtin_amdgcn_s_barrier(); SCHED0(); } while (0)
#define VMW(N) do { asm volatile("s_waitcnt vmcnt(" #N ")" ::: "memory"); SCHED0(); } while (0)
#define LGKM0() do { asm volatile("s_waitcnt lgkmcnt(0)" ::: "memory"); SCHED0(); } while (0)
#define MFMA16(a, b, c) __builtin_amdgcn_mfma_f32_16x16x32_bf16(a, b, c, 0, 0, 0)

// split 8 fp32 -> hi/lo bf16, store as uint4 pair (ds_write_b128)
__device__ __forceinline__ void split8_store(float4 v0, float4 v1,
                                             unsigned short* Hdst,
                                             unsigned short* Ldst) {
  float f[8] = {v0.x, v0.y, v0.z, v0.w, v1.x, v1.y, v1.z, v1.w};
  unsigned short hh[8], ll[8];
#pragma unroll
  for (int i = 0; i < 8; ++i) {
    hh[i] = f2bf(f[i]);
    ll[i] = f2bf(f[i] - bf2f(hh[i]));
  }
  *reinterpret_cast<uint4*>(Hdst) = make_uint4(pack2(hh[0], hh[1]), pack2(hh[2], hh[3]),
                                               pack2(hh[4], hh[5]), pack2(hh[6], hh[7]));
  *reinterpret_cast<uint4*>(Ldst) = make_uint4(pack2(ll[0], ll[1]), pack2(ll[2], ll[3]),
                                               pack2(ll[4], ll[5]), pack2(ll[6], ll[7]));
}

// split + additionally scatter hi-bf16 into the transpose buffer Tt[k][c-swizzled]
__device__ __forceinline__ void split8_store_tt(float4 v0, float4 v1,
                                                unsigned short* Hdst,
                                                unsigned short* Ldst,
                                                unsigned short* Ttb,
                                                int kslot, int c) {
  float f[8] = {v0.x, v0.y, v0.z, v0.w, v1.x, v1.y, v1.z, v1.w};
  unsigned short hh[8], ll[8];
#pragma unroll
  for (int i = 0; i < 8; ++i) {
    hh[i] = f2bf(f[i]);
    ll[i] = f2bf(f[i] - bf2f(hh[i]));
  }
  *reinterpret_cast<uint4*>(Hdst) = make_uint4(pack2(hh[0], hh[1]), pack2(hh[2], hh[3]),
                                               pack2(hh[4], hh[5]), pack2(hh[6], hh[7]));
  *reinterpret_cast<uint4*>(Ldst) = make_uint4(pack2(ll[0], ll[1]), pack2(ll[2], ll[3]),
                                               pack2(ll[4], ll[5]), pack2(ll[6], ll[7]));
#pragma unroll
  for (int i = 0; i < 8; ++i) {
    int g = ((c >> 3) ^ i ^ kslot) & 7;  // (c>>3) ^ (k&7) ^ (k>>3), k = kslot*8+i
    Ttb[(kslot * 8 + i) * 72 + g * 8 + (c & 7)] = hh[i];
  }
}

// -------- QB prep: Th/Tl[d][k] = split-bf16 of [Qm | Km] column d --------
__global__ __launch_bounds__(256) void qkm_split(const float* __restrict__ Qm,
                                                 const float* __restrict__ Km,
                                                 unsigned short* __restrict__ Th,
                                                 unsigned short* __restrict__ Tl) {
  __shared__ float lt[64][65];
  int k0 = blockIdx.x * 64;
  int half = blockIdx.y;
  const float* M = half ? Km : Qm;
  int t = threadIdx.x;
  int cl = (t & 15) * 4;
  int rl = t >> 4;
#pragma unroll
  for (int rr = 0; rr < 4; ++rr) {
    int r = rl + rr * 16;
    float4 v = *reinterpret_cast<const float4*>(&M[(long)(k0 + r) * 64 + cl]);
    lt[cl + 0][r] = v.x;
    lt[cl + 1][r] = v.y;
    lt[cl + 2][r] = v.z;
    lt[cl + 3][r] = v.w;
  }
  __syncthreads();
#pragma unroll
  for (int rr = 0; rr < 4; ++rr) {
    int c = rl + rr * 16;
    unsigned short h[4], lo[4];
#pragma unroll
    for (int i = 0; i < 4; ++i) {
      float f = lt[c][cl + i];
      h[i] = f2bf(f);
      lo[i] = f2bf(f - bf2f(h[i]));
    }
    *reinterpret_cast<uint2*>(&Th[(long)(half * 64 + c) * 1024 + k0 + cl]) =
        make_uint2(pack2(h[0], h[1]), pack2(h[2], h[3]));
    *reinterpret_cast<uint2*>(&Tl[(long)(half * 64 + c) * 1024 + k0 + cl]) =
        make_uint2(pack2(lo[0], lo[1]), pack2(lo[2], lo[3]));
  }
}

// -------- K1: qk split-bf16 out + fused x-transpose (xbT) --------------------
// Counted-vmcnt raw-barrier pipeline. Per K-tile (BK=32), vmem issue order:
//   store xbT (1) | x-load t+2 (2) | BAR | gld_lds D(t+2) (4) | VMW(7) | BAR
// VMW(7) (in-order vmcnt retirement) == "previous iteration's 7 ops done":
// D(t+1) landed, old store acked — each covered by a full iteration.
__global__ __launch_bounds__(256) void k1_mfma(const float* __restrict__ x,
                                               const unsigned short* __restrict__ Th,
                                               const unsigned short* __restrict__ Tl,
                                               unsigned short* __restrict__ qkh,
                                               unsigned short* __restrict__ qkl,
                                               unsigned short* __restrict__ xbT) {
  __shared__ unsigned short Dh[2][128 * 32];
  __shared__ unsigned short Dl[2][128 * 32];
  __shared__ unsigned short Xh[2][64 * 32];
  __shared__ unsigned short Xl[2][64 * 32];
  __shared__ unsigned short Tt[2][32 * 72];
  const int t = threadIdx.x;
  const int l = t & 63;
  const int w = t >> 6;
  const int wr = w >> 1, wc = w & 1;
  const long mBase = (long)blockIdx.x * 64;
  const int b = blockIdx.x >> 3;
  const int cBase = (blockIdx.x & 7) * 64;

  f32x4 acc[4][2];
#pragma unroll
  for (int m = 0; m < 4; ++m)
#pragma unroll
    for (int n = 0; n < 2; ++n) acc[m][n] = (f32x4){0.f, 0.f, 0.f, 0.f};

  const int xrow_l = t >> 2;
  const int kslot = t & 3;
  const int xsl = kslot ^ ((t >> 3) & 3);
  const int srcslot = (l & 3) ^ ((l >> 3) & 3);
  const int frag_off = (l & 15) * 32 + ((((l >> 4) ^ (l >> 1)) & 3) * 8);
  const float* xrow = x + (mBase + xrow_l) * 1024;

#define K1_LOADX(r0, r1, tt)                                                  \
  {                                                                           \
    r0 = *reinterpret_cast<const float4*>(&xrow[(tt) * 32 + kslot * 8]);      \
    r1 = *reinterpret_cast<const float4*>(&xrow[(tt) * 32 + kslot * 8 + 4]);  \
  }

#define K1_STAGE_D(tt, p)                                                     \
  {                                                                           \
    _Pragma("unroll") for (int c = 0; c < 2; ++c) {                           \
      int ch = c * 4 + w;                                                     \
      int row = ch * 16 + (l >> 2);                                           \
      gld_lds16(Th + (long)row * 1024 + (tt) * 32 + srcslot * 8, &Dh[p][ch * 512]); \
      gld_lds16(Tl + (long)row * 1024 + (tt) * 32 + srcslot * 8, &Dl[p][ch * 512]); \
    }                                                                         \
  }

#define K1_COMPUTE(p)                                                         \
  {                                                                           \
    bf16x8 dh[4], dl[4], xh[2], xl[2];                                        \
    _Pragma("unroll") for (int m = 0; m < 4; ++m) {                           \
      dh[m] = *reinterpret_cast<const bf16x8*>(&Dh[p][(wr * 64 + m * 16) * 32 + frag_off]); \
      dl[m] = *reinterpret_cast<const bf16x8*>(&Dl[p][(wr * 64 + m * 16) * 32 + frag_off]); \
    }                                                                         \
    _Pragma("unroll") for (int n = 0; n < 2; ++n) {                           \
      xh[n] = *reinterpret_cast<const bf16x8*>(&Xh[p][(wc * 32 + n * 16) * 32 + frag_off]); \
      xl[n] = *reinterpret_cast<const bf16x8*>(&Xl[p][(wc * 32 + n * 16) * 32 + frag_off]); \
    }                                                                         \
    _Pragma("unroll") for (int m = 0; m < 4; ++m)                             \
        _Pragma("unroll") for (int n = 0; n < 2; ++n) {                       \
      acc[m][n] = MFMA16(dh[m], xh[n], acc[m][n]);                            \
      acc[m][n] = MFMA16(dh[m], xl[n], acc[m][n]);                            \
      acc[m][n] = MFMA16(dl[m], xh[n], acc[m][n]);                            \
    }                                                                         \
  }

  // read one b128 row-slice from Tt[p] and store coalesced 16B to xbT
#define K1_WRITEBACK(p, kk)                                                   \
  {                                                                           \
    int n2 = t >> 3;                                                          \
    int g2 = t & 7;                                                           \
    int gs = (g2 ^ (n2 & 7) ^ (n2 >> 3)) & 7;                                 \
    uint4 vv = *reinterpret_cast<const uint4*>(&Tt[p][n2 * 72 + gs * 8]);     \
    *reinterpret_cast<uint4*>(                                                \
        &xbT[(long)b * 524288 + (long)((kk) + n2) * 512 + cBase + g2 * 8]) = vv; \
  }

  float4 xa0, xa1, xb0, xb1;

  // prologue: x(0)->A(2), D(0)(4), x(1)->B(2), split A->buf0, D(1)(4), VMW(6)
  K1_LOADX(xa0, xa1, 0);
  K1_STAGE_D(0, 0);
  K1_LOADX(xb0, xb1, 1);
  split8_store_tt(xa0, xa1, &Xh[0][xrow_l * 32 + xsl * 8], &Xl[0][xrow_l * 32 + xsl * 8],
                  Tt[0], kslot, xrow_l);
  K1_STAGE_D(1, 1);
  VMW(6);
  LGKM0();
  NTBAR();

  for (int kt = 0; kt < 32; kt += 2) {
    // even body: tile kt, p=0; split(B=x(kt+1)) -> buf1; load x(kt+2) -> A
    {
      const int tn = (kt + 2 < 32) ? kt + 2 : 31;
      K1_COMPUTE(0);
      K1_WRITEBACK(0, kt * 32);
      K1_LOADX(xa0, xa1, tn);
      split8_store_tt(xb0, xb1, &Xh[1][xrow_l * 32 + xsl * 8], &Xl[1][xrow_l * 32 + xsl * 8],
                      Tt[1], kslot, xrow_l);
      LGKM0();
      NTBAR();
      K1_STAGE_D(tn, 0);
      VMW(7);
      NTBAR();
    }
    // odd body: tile kt+1, p=1; split(A=x(kt+2)) -> buf0; load x(kt+3) -> B
    {
      const int tn = (kt + 3 < 32) ? kt + 3 : 31;
      K1_COMPUTE(1);
      K1_WRITEBACK(1, (kt + 1) * 32);
      K1_LOADX(xb0, xb1, tn);
      split8_store_tt(xa0, xa1, &Xh[0][xrow_l * 32 + xsl * 8], &Xl[0][xrow_l * 32 + xsl * 8],
                      Tt[0], kslot, xrow_l);
      LGKM0();
      NTBAR();
      K1_STAGE_D(tn, 1);
      VMW(7);
      NTBAR();
    }
  }

#pragma unroll
  for (int m = 0; m < 4; ++m)
#pragma unroll
    for (int n = 0; n < 2; ++n) {
      int d0 = wr * 64 + m * 16 + (l >> 4) * 4;
      long xr = mBase + wc * 32 + n * 16 + (l & 15);
      unsigned short h4[4], l4[4];
#pragma unroll
      for (int reg = 0; reg < 4; ++reg) {
        float v = acc[m][n][reg];
        h4[reg] = f2bf(v);
        l4[reg] = f2bf(v - bf2f(h4[reg]));
      }
      *reinterpret_cast<uint2*>(&qkh[xr * 128 + d0]) =
          make_uint2(pack2(h4[0], h4[1]), pack2(h4[2], h4[3]));
      *reinterpret_cast<uint2*>(&qkl[xr * 128 + d0]) =
          make_uint2(pack2(l4[0], l4[1]), pack2(l4[2], l4[3]));
    }
#undef K1_LOADX
#undef K1_STAGE_D
#undef K1_COMPUTE
#undef K1_WRITEBACK
}

// -------- K2a: st[b,j,i] = exp(sigmoid(q_i . k_j)), split-bf16 MFMA -----------
// Stages pre-split qkh/qkl via global_load_lds (lane-linear dest, swizzled src).
__global__ __launch_bounds__(256) void k2a_mfma(const unsigned short* __restrict__ qkh,
                                                const unsigned short* __restrict__ qkl,
                                                unsigned short* __restrict__ st) {
  __shared__ unsigned short Ah[128 * 64];
  __shared__ unsigned short Al[128 * 64];
  __shared__ unsigned short Bh[128 * 64];
  __shared__ unsigned short Bl[128 * 64];
  const int t = threadIdx.x;
  const int l = t & 63;
  const int w = t >> 6;
  const int wr = w >> 1, wc = w & 1;

  const int cpx = gridDim.x >> 3;
  const int orig = blockIdx.x;
  const int lw = (orig & 7) * cpx + (orig >> 3);
  const int b = lw >> 4;
  const int tile = lw & 15;
  const int iBase = (tile >> 2) * 128;
  const int jBase = (tile & 3) * 128;
  const long bq = (long)b * 512;

  const int sg = (l & 7) ^ (l >> 3);
#pragma unroll
  for (int c4 = 0; c4 < 4; ++c4) {
    int rb = w * 32 + c4 * 8;
    long rowA = bq + iBase + rb + (l >> 3);
    long rowB = bq + jBase + rb + (l >> 3);
    gld_lds16(qkh + rowA * 128 + sg * 8, &Ah[rb * 64]);
    gld_lds16(qkl + rowA * 128 + sg * 8, &Al[rb * 64]);
    gld_lds16(qkh + rowB * 128 + 64 + sg * 8, &Bh[rb * 64]);
    gld_lds16(qkl + rowB * 128 + 64 + sg * 8, &Bl[rb * 64]);
  }
  __syncthreads();

  f32x4 acc[4][4];
#pragma unroll
  for (int m = 0; m < 4; ++m)
#pragma unroll
    for (int n = 0; n < 4; ++n) acc[m][n] = (f32x4){0.f, 0.f, 0.f, 0.f};

#pragma unroll
  for (int ks = 0; ks < 2; ++ks) {
    bf16x8 ah[4], al4[4], bh[4], bl4[4];
#pragma unroll
    for (int m = 0; m < 4; ++m) {
      int row = wr * 64 + m * 16 + (l & 15);
      int off = row * 64 + ((ks * 4 + (l >> 4)) ^ (row & 7)) * 8;
      ah[m] = *reinterpret_cast<const bf16x8*>(&Ah[off]);
      al4[m] = *reinterpret_cast<const bf16x8*>(&Al[off]);
    }
#pragma unroll
    for (int n = 0; n < 4; ++n) {
      int row = wc * 64 + n * 16 + (l & 15);
      int off = row * 64 + ((ks * 4 + (l >> 4)) ^ (row & 7)) * 8;
      bh[n] = *reinterpret_cast<const bf16x8*>(&Bh[off]);
      bl4[n] = *reinterpret_cast<const bf16x8*>(&Bl[off]);
    }
#pragma unroll
    for (int m = 0; m < 4; ++m)
#pragma unroll
      for (int n = 0; n < 4; ++n) {
        acc[m][n] = MFMA16(ah[m], bh[n], acc[m][n]);
        acc[m][n] = MFMA16(ah[m], bl4[n], acc[m][n]);
        acc[m][n] = MFMA16(al4[m], bh[n], acc[m][n]);
      }
  }

  unsigned short* sb = st + (long)b * 512 * 512;
#pragma unroll
  for (int m = 0; m < 4; ++m)
#pragma unroll
    for (int n = 0; n < 4; ++n) {
      int i0 = iBase + wr * 64 + m * 16 + (l >> 4) * 4;
      int j = jBase + wc * 64 + n * 16 + (l & 15);
      unsigned short p[4];
#pragma unroll
      for (int reg = 0; reg < 4; ++reg) {
        float sg2 = 1.0f / (1.0f + __expf(-acc[m][n][reg]));
        p[reg] = f2bf(__expf(sg2));
      }
      *reinterpret_cast<uint2*>(&sb[(long)j * 512 + i0]) = *reinterpret_cast<uint2*>(p);
    }
}

// -------- K2b: per-row (j) sums of st -> rsum = 1/sum, attbias = (st.bias)/sum ----
__global__ __launch_bounds__(256) void k2b_rsum(const unsigned short* __restrict__ st,
                                                const float* __restrict__ bias,
                                                float* __restrict__ rsum,
                                                float* __restrict__ attbias) {
  int jg = blockIdx.x * 4 + (threadIdx.x >> 6);
  int l = threadIdx.x & 63;
  const unsigned short* row = st + (long)jg * 512 + l * 8;
  ushort4 u0 = *reinterpret_cast<const ushort4*>(row);
  ushort4 u1 = *reinterpret_cast<const ushort4*>(row + 4);
  float4 b0 = *reinterpret_cast<const float4*>(&bias[l * 8]);
  float4 b1 = *reinterpret_cast<const float4*>(&bias[l * 8 + 4]);
  float f0 = bf2f(u0.x), f1 = bf2f(u0.y), f2 = bf2f(u0.z), f3 = bf2f(u0.w);
  float f4 = bf2f(u1.x), f5 = bf2f(u1.y), f6 = bf2f(u1.z), f7 = bf2f(u1.w);
  float sum = (f0 + f1) + (f2 + f3) + ((f4 + f5) + (f6 + f7));
  float sumb = f0 * b0.x + f1 * b0.y + f2 * b0.z + f3 * b0.w +
               f4 * b1.x + f5 * b1.y + f6 * b1.z + f7 * b1.w;
#pragma unroll
  for (int off = 32; off > 0; off >>= 1) {
    sum += __shfl_down(sum, off);
    sumb += __shfl_down(sumb, off);
  }
  if (l == 0) {
    float r = 1.0f / sum;
    rsum[jg] = r;
    attbias[jg] = sumb * r;
  }
}

// -------- transpose + fp32->bf16 convert: out[c][r] = bf16(in[r][c]) --------
__global__ __launch_bounds__(256) void transpose_conv(const float* __restrict__ in,
                                                      unsigned short* __restrict__ out,
                                                      int inRows, int inCols,
                                                      long inBatch, long outBatch) {
  __shared__ unsigned short lt[64][65];
  int b = blockIdx.z;
  int r0 = blockIdx.y * 64;
  int c0 = blockIdx.x * 64;
  const float* I = in + (long)b * inBatch;
  unsigned short* O = out + (long)b * outBatch;
  int t = threadIdx.x;
  int cl = (t & 15) * 4;
  int rl = t >> 4;
#pragma unroll
  for (int rr = 0; rr < 4; ++rr) {
    int r = rl + rr * 16;
    float4 v = *reinterpret_cast<const float4*>(&I[(long)(r0 + r) * inCols + c0 + cl]);
    lt[cl + 0][r] = f2bf(v.x);
    lt[cl + 1][r] = f2bf(v.y);
    lt[cl + 2][r] = f2bf(v.z);
    lt[cl + 3][r] = f2bf(v.w);
  }
  __syncthreads();
#pragma unroll
  for (int rr = 0; rr < 4; ++rr) {
    int c = rl + rr * 16;
    unsigned short v[4] = {lt[c][cl], lt[c][cl + 1], lt[c][cl + 2], lt[c][cl + 3]};
    *reinterpret_cast<uint2*>(&O[(long)(c0 + c) * inRows + r0 + cl]) =
        *reinterpret_cast<uint2*>(&v[0]);
  }
}

// ======== 256x256 bf16 MFMA GEMM, BK=64, 8 waves, 8-PHASE schedule (m201) ========
template <int MODE>
__global__ __launch_bounds__(512) void mfma_nt256(const unsigned short* __restrict__ Abase,
                                                  const unsigned short* __restrict__ Bbase,
                                                  const float* __restrict__ rowscale,
                                                  unsigned short* __restrict__ Wout,
                                                  float* __restrict__ Fout) {
  __shared__ unsigned short As[2][256 * 64];
  __shared__ unsigned short Bs[2][256 * 64];
  const int t = threadIdx.x;
  const int l = t & 63;
  const int w = t >> 6;          // 0..7
  const int wr = w >> 2;         // 0..1  (M: 2 x 128)
  const int wc = w & 3;          // 0..3  (N: 4 x 64)

  const int cpx = gridDim.x >> 3;
  const int orig = blockIdx.x;
  const int lw = (orig & 7) * cpx + (orig >> 3);
  const int TPB_SH = (MODE == 0) ? 2 : 3;
  const int b = lw >> TPB_SH;
  const int tile = lw & ((1 << TPB_SH) - 1);
  const int mBase = (tile >> 1) * 256;
  const int nBase = (tile & 1) * 256;

  const unsigned short* Ag = Abase + ((MODE == 0) ? 0L : (long)b * (1024 * 512)) + (long)mBase * 512;
  const unsigned short* Bg = Bbase + (long)b * (512 * 512) + (long)nBase * 512;

  f32x4 acc[8][4];
#pragma unroll
  for (int m = 0; m < 8; ++m)
#pragma unroll
    for (int n = 0; n < 4; ++n) acc[m][n] = (f32x4){0.f, 0.f, 0.f, 0.f};

  const int srcslot = (l & 7) ^ (l >> 3);
  const int so0 = ((l >> 4) ^ (l & 7)) * 8;
  const int so1 = ((4 + (l >> 4)) ^ (l & 7)) * 8;

#define STG_A(p, tt, pr)                                                       \
  gld_lds16(Ag + (long)((pr) * 64 + w * 8 + (l >> 3)) * 512 + (tt) * 64 + srcslot * 8, \
            &As[p][((pr) * 64 + w * 8) * 64]);
#define STG_B(p, tt, pr)                                                       \
  gld_lds16(Bg + (long)((pr) * 64 + w * 8 + (l >> 3)) * 512 + (tt) * 64 + srcslot * 8, \
            &Bs[p][((pr) * 64 + w * 8) * 64]);

#define PHASE(p, q, STAGE_STMT, VMSTMT)                                        \
  {                                                                            \
    bf16x8 a00 = *reinterpret_cast<const bf16x8*>(                             \
        &As[p][(wr * 128 + (2 * (q)) * 16 + (l & 15)) * 64 + so0]);            \
    bf16x8 a01 = *reinterpret_cast<const bf16x8*>(                             \
        &As[p][(wr * 128 + (2 * (q)) * 16 + (l & 15)) * 64 + so1]);            \
    bf16x8 a10 = *reinterpret_cast<const bf16x8*>(                             \
        &As[p][(wr * 128 + (2 * (q) + 1) * 16 + (l & 15)) * 64 + so0]);        \
    bf16x8 a11 = *reinterpret_cast<const bf16x8*>(                             \
        &As[p][(wr * 128 + (2 * (q) + 1) * 16 + (l & 15)) * 64 + so1]);        \
    if ((q) == 0) {                                                            \
      _Pragma("unroll") for (int n = 0; n < 4; ++n) {                          \
        bfr0[n] = *reinterpret_cast<const bf16x8*>(                            \
            &Bs[p][(wc * 64 + n * 16 + (l & 15)) * 64 + so0]);                 \
        bfr1[n] = *reinterpret_cast<const bf16x8*>(                            \
            &Bs[p][(wc * 64 + n * 16 + (l & 15)) * 64 + so1]);                 \
      }                                                                        \
    }                                                                          \
    STAGE_STMT;                                                                \
    SCHED0();                                                                  \
    __builtin_amdgcn_s_barrier();                                              \
    LGKM0();                                                                   \
    __builtin_amdgcn_s_setprio(1);                                             \
    _Pragma("unroll") for (int n = 0; n < 4; ++n) {                            \
      acc[2 * (q)][n] = MFMA16(a00, bfr0[n], acc[2 * (q)][n]);                 \
      acc[2 * (q)][n] = MFMA16(a01, bfr1[n], acc[2 * (q)][n]);                 \
      acc[2 * (q) + 1][n] = MFMA16(a10, bfr0[n], acc[2 * (q) + 1][n]);         \
      acc[2 * (q) + 1][n] = MFMA16(a11, bfr1[n], acc[2 * (q) + 1][n]);         \
    }                                                                          \
    __builtin_amdgcn_s_setprio(0);                                             \
    VMSTMT;                                                                    \
    NTBAR();                                                                   \
  }

  bf16x8 bfr0[4], bfr1[4];

  // prologue: buf0 <- tile0 (8 loads), buf1 <- B0,B1,Ha of tile1 (6 loads)
  STG_A(0, 0, 0); STG_A(0, 0, 1); STG_A(0, 0, 2); STG_A(0, 0, 3);
  STG_B(0, 0, 0); STG_B(0, 0, 1); STG_B(0, 0, 2); STG_B(0, 0, 3);
  STG_B(1, 1, 0); STG_B(1, 1, 1); STG_B(1, 1, 2); STG_B(1, 1, 3);
  STG_A(1, 1, 0); STG_A(1, 1, 2);
  VMW(6);
  NTBAR();

  for (int it = 0; it < 4; ++it) {
    const int t1 = 2 * it + 1;
    const int t2 = (2 * it + 2 < 8) ? 2 * it + 2 : 7;
    const int t3 = (2 * it + 3 < 8) ? 2 * it + 3 : 7;
    PHASE(0, 0, { STG_A(1, t1, 1); STG_A(1, t1, 3); }, );
    PHASE(0, 1, { STG_B(0, t2, 0); STG_B(0, t2, 1); }, VMW(10));
    PHASE(0, 2, { STG_B(0, t2, 2); STG_B(0, t2, 3); }, );
    PHASE(0, 3, { STG_A(0, t2, 0); STG_A(0, t2, 2); }, VMW(8));
    PHASE(1, 0, { STG_A(0, t2, 1); STG_A(0, t2, 3); }, );
    PHASE(1, 1, { STG_B(1, t3, 0); STG_B(1, t3, 1); }, VMW(10));
    PHASE(1, 2, { STG_B(1, t3, 2); STG_B(1, t3, 3); }, );
    PHASE(1, 3, { STG_A(1, t3, 0); STG_A(1, t3, 2); }, VMW(8));
  }
#undef PHASE
#undef STG_A
#undef STG_B

  if (MODE == 0) {
    unsigned short* W = Wout + (long)b * (512 * 512);
#pragma unroll
    for (int n = 0; n < 4; ++n) {
      int j = nBase + wc * 64 + n * 16 + (l & 15);
      float rs = rowscale[b * 512 + j];
#pragma unroll
      for (int m = 0; m < 8; ++m) {
        int c0 = mBase + wr * 128 + m * 16 + (l >> 4) * 4;
        unsigned short p[4];
#pragma unroll
        for (int reg = 0; reg < 4; ++reg) p[reg] = f2bf(acc[m][n][reg] * rs);
        *reinterpret_cast<uint2*>(&W[(long)j * 512 + c0]) = *reinterpret_cast<uint2*>(p);
      }
    }
  } else {
    float* O = Fout + (long)b * (512 * 1024);
#pragma unroll
    for (int n = 0; n < 4; ++n) {
      int j = nBase + wc * 64 + n * 16 + (l & 15);
      float ab = rowscale[b * 512 + j];
#pragma unroll
      for (int m = 0; m < 8; ++m) {
        int n0 = mBase + wr * 128 + m * 16 + (l >> 4) * 4;
        *reinterpret_cast<float4*>(&O[(long)j * 1024 + n0]) =
            make_float4(acc[m][n][0] + ab, acc[m][n][1] + ab,
                        acc[m][n][2] + ab, acc[m][n][3] + ab);
      }
    }
  }
}

extern "C" void kernel_launch(void* const* d_in, const int* in_sizes, int n_in,
                              void* d_out, int out_size, void* d_ws, size_t ws_size,
                              hipStream_t stream) {
  const float* x  = (const float*)d_in[0];
  const float* Qm = (const float*)d_in[1];
  const float* Km = (const float*)d_in[2];
  const float* vw = (const float*)d_in[3];
  const float* vb = (const float*)d_in[4];
  float* out = (float*)d_out;

  float* ws = (float*)d_ws;
  unsigned short* qkh  = (unsigned short*)ws;                         // 4,194,304 ush
  unsigned short* qkl  = qkh + 4194304;                               // 4,194,304 ush
  unsigned short* st   = (unsigned short*)(ws + 4194304);             // spans 8,388,608 f
  unsigned short* weff = (unsigned short*)(ws + 4194304 + 8388608);   // spans 8,388,608 f
  unsigned short* xbT  = (unsigned short*)(ws + 4194304 + 16777216);  // spans 16,777,216 f
  unsigned short* vwT  = (unsigned short*)(ws + 4194304 + 33554432);  // spans 131,072 f
  unsigned short* qkTh = (unsigned short*)(ws + 4194304 + 33554432 + 131072);  // 65,536 f
  unsigned short* qkTl = qkTh + 131072;                               // 65,536 f
  float* rsum    = ws + 4194304 + 33554432 + 131072 + 131072;         // 32,768 f
  float* attbias = rsum + 32768;                                      // 32,768 f

  // T2: vwT[c][i] = bf16(vw[i][c])
  transpose_conv<<<dim3(8, 8, 1), 256, 0, stream>>>(vw, vwT, 512, 512, 0L, 0L);
  // T3: split-transposed [Qm|Km] -> qkTh/qkTl [128][1024]
  qkm_split<<<dim3(16, 2), 256, 0, stream>>>(Qm, Km, qkTh, qkTl);
  // K1: qkh/qkl = split(x @ [Qm|Km]) + fused xbT transpose (counted-vmcnt pipeline)
  k1_mfma<<<512, 256, 0, stream>>>(x, qkTh, qkTl, qkh, qkl, xbT);
  // K2a: st[b,j,i] = exp(sigmoid(q_i . k_j)), gld_lds staging of qkh/qkl
  k2a_mfma<<<1024, 256, 0, stream>>>(qkh, qkl, st);
  // K2b: rsum, attbias
  k2b_rsum<<<8192, 256, 0, stream>>>(st, vb, rsum, attbias);
  // K3: weff = diag(rsum) . st . Vw   (A=vwT, B=st), 4 tiles/b
  mfma_nt256<0><<<256, 512, 0, stream>>>(vwT, st, rsum, weff, nullptr);
  // K4: out = weff . xf + attbias     (A=xbT, B=weff), 8 tiles/b
  mfma_nt256<1><<<512, 512, 0, stream>>>(xbT, weff, attbias, nullptr, out);
}

// Round 16
// 185.386 us; speedup vs baseline: 1.3158x; 1.0293x over previous
//
#include <hip/hip_runtime.h>

typedef __attribute__((ext_vector_type(8))) short bf16x8;
typedef __attribute__((ext_vector_type(4))) float f32x4;

__device__ __forceinline__ unsigned short f2bf(float f) {
  unsigned u = __builtin_bit_cast(unsigned, f);
  unsigned r = (u + 0x7FFFu + ((u >> 16) & 1u)) >> 16;
  return (unsigned short)r;
}
__device__ __forceinline__ float bf2f(unsigned short h) {
  return __builtin_bit_cast(float, (unsigned)h << 16);
}
__device__ __forceinline__ unsigned pack2(unsigned short a, unsigned short b) {
  return (unsigned)a | ((unsigned)b << 16);
}

__device__ __forceinline__ void gld_lds16(const void* g, void* l) {
  __builtin_amdgcn_global_load_lds(
      (const __attribute__((address_space(1))) unsigned int*)g,
      (__attribute__((address_space(3))) unsigned int*)l, 16, 0, 0);
}

#define SCHED0() __builtin_amdgcn_sched_barrier(0)
#define NTBAR() do { SCHED0(); __builtin_amdgcn_s_barrier(); SCHED0(); } while (0)
#define VMW(N) do { asm volatile("s_waitcnt vmcnt(" #N ")" ::: "memory"); SCHED0(); } while (0)
#define LGKM0() do { asm volatile("s_waitcnt lgkmcnt(0)" ::: "memory"); SCHED0(); } while (0)
#define MFMA16(a, b, c) __builtin_amdgcn_mfma_f32_16x16x32_bf16(a, b, c, 0, 0, 0)

// split 8 fp32 -> hi/lo bf16, store as uint4 pair; return packed hi words
__device__ __forceinline__ uint4 split8_store_h(float4 v0, float4 v1,
                                                unsigned short* Hdst,
                                                unsigned short* Ldst) {
  float f[8] = {v0.x, v0.y, v0.z, v0.w, v1.x, v1.y, v1.z, v1.w};
  unsigned short hh[8], ll[8];
#pragma unroll
  for (int i = 0; i < 8; ++i) {
    hh[i] = f2bf(f[i]);
    ll[i] = f2bf(f[i] - bf2f(hh[i]));
  }
  uint4 hv = make_uint4(pack2(hh[0], hh[1]), pack2(hh[2], hh[3]),
                        pack2(hh[4], hh[5]), pack2(hh[6], hh[7]));
  *reinterpret_cast<uint4*>(Hdst) = hv;
  *reinterpret_cast<uint4*>(Ldst) = make_uint4(pack2(ll[0], ll[1]), pack2(ll[2], ll[3]),
                                               pack2(ll[4], ll[5]), pack2(ll[6], ll[7]));
  return hv;
}

// -------- QB prep: Th/Tl[d][k] = split-bf16 of [Qm | Km] column d --------
__global__ __launch_bounds__(256) void qkm_split(const float* __restrict__ Qm,
                                                 const float* __restrict__ Km,
                                                 unsigned short* __restrict__ Th,
                                                 unsigned short* __restrict__ Tl) {
  __shared__ float lt[64][65];
  int k0 = blockIdx.x * 64;
  int half = blockIdx.y;
  const float* M = half ? Km : Qm;
  int t = threadIdx.x;
  int cl = (t & 15) * 4;
  int rl = t >> 4;
#pragma unroll
  for (int rr = 0; rr < 4; ++rr) {
    int r = rl + rr * 16;
    float4 v = *reinterpret_cast<const float4*>(&M[(long)(k0 + r) * 64 + cl]);
    lt[cl + 0][r] = v.x;
    lt[cl + 1][r] = v.y;
    lt[cl + 2][r] = v.z;
    lt[cl + 3][r] = v.w;
  }
  __syncthreads();
#pragma unroll
  for (int rr = 0; rr < 4; ++rr) {
    int c = rl + rr * 16;
    unsigned short h[4], lo[4];
#pragma unroll
    for (int i = 0; i < 4; ++i) {
      float f = lt[c][cl + i];
      h[i] = f2bf(f);
      lo[i] = f2bf(f - bf2f(h[i]));
    }
    *reinterpret_cast<uint2*>(&Th[(long)(half * 64 + c) * 1024 + k0 + cl]) =
        make_uint2(pack2(h[0], h[1]), pack2(h[2], h[3]));
    *reinterpret_cast<uint2*>(&Tl[(long)(half * 64 + c) * 1024 + k0 + cl]) =
        make_uint2(pack2(lo[0], lo[1]), pack2(lo[2], lo[3]));
  }
}

// -------- K1: qk split-bf16 out + fused x-transpose, single-Tt / 3 blocks/CU ----
// Counted-vmcnt raw-barrier pipeline; per K-tile segment (vmem order):
//   store xbT(1) | x-load t+2 (2) | BAR1 | scatter Tt(t+1) | gld_lds D(t+2) (4)
//   | LGKM0 | VMW(7) | BAR2
// Tt hazard separation: WRITEBACK(t) reads Tt before BAR1; scatter(t+1) writes
// Tt after BAR1; scatter -> LGKM0+BAR2 -> next WRITEBACK(t+1) read. Single Tt
// buffer (4.6 KB) puts LDS at 52.5 KB -> 3 blocks/CU (was 2).
__global__ __launch_bounds__(256) void k1_mfma(const float* __restrict__ x,
                                               const unsigned short* __restrict__ Th,
                                               const unsigned short* __restrict__ Tl,
                                               unsigned short* __restrict__ qkh,
                                               unsigned short* __restrict__ qkl,
                                               unsigned short* __restrict__ xbT) {
  __shared__ unsigned short Dh[2][128 * 32];
  __shared__ unsigned short Dl[2][128 * 32];
  __shared__ unsigned short Xh[2][64 * 32];
  __shared__ unsigned short Xl[2][64 * 32];
  __shared__ unsigned short Tt[32 * 72];
  const int t = threadIdx.x;
  const int l = t & 63;
  const int w = t >> 6;
  const int wr = w >> 1, wc = w & 1;
  const long mBase = (long)blockIdx.x * 64;
  const int b = blockIdx.x >> 3;
  const int cBase = (blockIdx.x & 7) * 64;

  f32x4 acc[4][2];
#pragma unroll
  for (int m = 0; m < 4; ++m)
#pragma unroll
    for (int n = 0; n < 2; ++n) acc[m][n] = (f32x4){0.f, 0.f, 0.f, 0.f};

  const int xrow_l = t >> 2;
  const int kslot = t & 3;
  const int xsl = kslot ^ ((t >> 3) & 3);
  const int srcslot = (l & 3) ^ ((l >> 3) & 3);
  const int frag_off = (l & 15) * 32 + ((((l >> 4) ^ (l >> 1)) & 3) * 8);
  const float* xrow = x + (mBase + xrow_l) * 1024;

#define K1_LOADX(r0, r1, tt)                                                  \
  {                                                                           \
    r0 = *reinterpret_cast<const float4*>(&xrow[(tt) * 32 + kslot * 8]);      \
    r1 = *reinterpret_cast<const float4*>(&xrow[(tt) * 32 + kslot * 8 + 4]);  \
  }

#define K1_STAGE_D(tt, p)                                                     \
  {                                                                           \
    _Pragma("unroll") for (int c = 0; c < 2; ++c) {                           \
      int ch = c * 4 + w;                                                     \
      int row = ch * 16 + (l >> 2);                                           \
      gld_lds16(Th + (long)row * 1024 + (tt) * 32 + srcslot * 8, &Dh[p][ch * 512]); \
      gld_lds16(Tl + (long)row * 1024 + (tt) * 32 + srcslot * 8, &Dl[p][ch * 512]); \
    }                                                                         \
  }

#define K1_COMPUTE(p)                                                         \
  {                                                                           \
    bf16x8 dh[4], dl[4], xh[2], xl[2];                                        \
    _Pragma("unroll") for (int m = 0; m < 4; ++m) {                           \
      dh[m] = *reinterpret_cast<const bf16x8*>(&Dh[p][(wr * 64 + m * 16) * 32 + frag_off]); \
      dl[m] = *reinterpret_cast<const bf16x8*>(&Dl[p][(wr * 64 + m * 16) * 32 + frag_off]); \
    }                                                                         \
    _Pragma("unroll") for (int n = 0; n < 2; ++n) {                           \
      xh[n] = *reinterpret_cast<const bf16x8*>(&Xh[p][(wc * 32 + n * 16) * 32 + frag_off]); \
      xl[n] = *reinterpret_cast<const bf16x8*>(&Xl[p][(wc * 32 + n * 16) * 32 + frag_off]); \
    }                                                                         \
    _Pragma("unroll") for (int m = 0; m < 4; ++m)                             \
        _Pragma("unroll") for (int n = 0; n < 2; ++n) {                       \
      acc[m][n] = MFMA16(dh[m], xh[n], acc[m][n]);                            \
      acc[m][n] = MFMA16(dh[m], xl[n], acc[m][n]);                            \
      acc[m][n] = MFMA16(dl[m], xh[n], acc[m][n]);                            \
    }                                                                         \
  }

  // scatter packed hi words hv (this thread's 8 k-elements at column xrow_l) into Tt
#define K1_SCATTER(hv)                                                        \
  {                                                                           \
    unsigned short e[8] = {                                                   \
        (unsigned short)(hv.x & 0xffff), (unsigned short)(hv.x >> 16),        \
        (unsigned short)(hv.y & 0xffff), (unsigned short)(hv.y >> 16),        \
        (unsigned short)(hv.z & 0xffff), (unsigned short)(hv.z >> 16),        \
        (unsigned short)(hv.w & 0xffff), (unsigned short)(hv.w >> 16)};       \
    _Pragma("unroll") for (int i = 0; i < 8; ++i) {                           \
      int g = ((xrow_l >> 3) ^ i ^ kslot) & 7;                                \
      Tt[(kslot * 8 + i) * 72 + g * 8 + (xrow_l & 7)] = e[i];                 \
    }                                                                         \
  }

  // read one b128 row-slice from Tt and store coalesced 16B to xbT
#define K1_WRITEBACK(kk)                                                      \
  {                                                                           \
    int n2 = t >> 3;                                                          \
    int g2 = t & 7;                                                           \
    int gs = (g2 ^ (n2 & 7) ^ (n2 >> 3)) & 7;                                 \
    uint4 vv = *reinterpret_cast<const uint4*>(&Tt[n2 * 72 + gs * 8]);        \
    *reinterpret_cast<uint4*>(                                                \
        &xbT[(long)b * 524288 + (long)((kk) + n2) * 512 + cBase + g2 * 8]) = vv; \
  }

  float4 xa0, xa1, xb0, xb1;
  uint4 hva, hvb;

  // prologue: x(0)->A(2), D(0)(4), x(1)->B(2), split A->buf0 + scatter tile0,
  // D(1)(4), VMW(6)
  K1_LOADX(xa0, xa1, 0);
  K1_STAGE_D(0, 0);
  K1_LOADX(xb0, xb1, 1);
  hva = split8_store_h(xa0, xa1, &Xh[0][xrow_l * 32 + xsl * 8], &Xl[0][xrow_l * 32 + xsl * 8]);
  K1_SCATTER(hva);
  K1_STAGE_D(1, 1);
  VMW(6);
  LGKM0();
  NTBAR();

  for (int kt = 0; kt < 32; kt += 2) {
    // even segment: tile kt (buf0); X(kt+1)->buf1; Tt := tile kt+1 after BAR1
    {
      const int tn = (kt + 2 < 32) ? kt + 2 : 31;
      K1_COMPUTE(0);
      K1_WRITEBACK(kt * 32);
      K1_LOADX(xa0, xa1, tn);
      hvb = split8_store_h(xb0, xb1, &Xh[1][xrow_l * 32 + xsl * 8], &Xl[1][xrow_l * 32 + xsl * 8]);
      LGKM0();
      NTBAR();
      K1_SCATTER(hvb);
      K1_STAGE_D(tn, 0);
      LGKM0();
      VMW(7);
      NTBAR();
    }
    // odd segment: tile kt+1 (buf1); X(kt+2)->buf0; Tt := tile kt+2 after BAR1
    {
      const int tn = (kt + 3 < 32) ? kt + 3 : 31;
      K1_COMPUTE(1);
      K1_WRITEBACK((kt + 1) * 32);
      K1_LOADX(xb0, xb1, tn);
      hva = split8_store_h(xa0, xa1, &Xh[0][xrow_l * 32 + xsl * 8], &Xl[0][xrow_l * 32 + xsl * 8]);
      LGKM0();
      NTBAR();
      K1_SCATTER(hva);
      K1_STAGE_D(tn, 1);
      LGKM0();
      VMW(7);
      NTBAR();
    }
  }

#pragma unroll
  for (int m = 0; m < 4; ++m)
#pragma unroll
    for (int n = 0; n < 2; ++n) {
      int d0 = wr * 64 + m * 16 + (l >> 4) * 4;
      long xr = mBase + wc * 32 + n * 16 + (l & 15);
      unsigned short h4[4], l4[4];
#pragma unroll
      for (int reg = 0; reg < 4; ++reg) {
        float v = acc[m][n][reg];
        h4[reg] = f2bf(v);
        l4[reg] = f2bf(v - bf2f(h4[reg]));
      }
      *reinterpret_cast<uint2*>(&qkh[xr * 128 + d0]) =
          make_uint2(pack2(h4[0], h4[1]), pack2(h4[2], h4[3]));
      *reinterpret_cast<uint2*>(&qkl[xr * 128 + d0]) =
          make_uint2(pack2(l4[0], l4[1]), pack2(l4[2], l4[3]));
    }
#undef K1_LOADX
#undef K1_STAGE_D
#undef K1_COMPUTE
#undef K1_SCATTER
#undef K1_WRITEBACK
}

// -------- K2a: st[b,j,i] = exp(sigmoid(q_i . k_j)), split-bf16 MFMA -----------
__global__ __launch_bounds__(256) void k2a_mfma(const unsigned short* __restrict__ qkh,
                                                const unsigned short* __restrict__ qkl,
                                                unsigned short* __restrict__ st) {
  __shared__ unsigned short Ah[128 * 64];
  __shared__ unsigned short Al[128 * 64];
  __shared__ unsigned short Bh[128 * 64];
  __shared__ unsigned short Bl[128 * 64];
  const int t = threadIdx.x;
  const int l = t & 63;
  const int w = t >> 6;
  const int wr = w >> 1, wc = w & 1;

  const int cpx = gridDim.x >> 3;
  const int orig = blockIdx.x;
  const int lw = (orig & 7) * cpx + (orig >> 3);
  const int b = lw >> 4;
  const int tile = lw & 15;
  const int iBase = (tile >> 2) * 128;
  const int jBase = (tile & 3) * 128;
  const long bq = (long)b * 512;

  const int sg = (l & 7) ^ (l >> 3);
#pragma unroll
  for (int c4 = 0; c4 < 4; ++c4) {
    int rb = w * 32 + c4 * 8;
    long rowA = bq + iBase + rb + (l >> 3);
    long rowB = bq + jBase + rb + (l >> 3);
    gld_lds16(qkh + rowA * 128 + sg * 8, &Ah[rb * 64]);
    gld_lds16(qkl + rowA * 128 + sg * 8, &Al[rb * 64]);
    gld_lds16(qkh + rowB * 128 + 64 + sg * 8, &Bh[rb * 64]);
    gld_lds16(qkl + rowB * 128 + 64 + sg * 8, &Bl[rb * 64]);
  }
  __syncthreads();

  f32x4 acc[4][4];
#pragma unroll
  for (int m = 0; m < 4; ++m)
#pragma unroll
    for (int n = 0; n < 4; ++n) acc[m][n] = (f32x4){0.f, 0.f, 0.f, 0.f};

#pragma unroll
  for (int ks = 0; ks < 2; ++ks) {
    bf16x8 ah[4], al4[4], bh[4], bl4[4];
#pragma unroll
    for (int m = 0; m < 4; ++m) {
      int row = wr * 64 + m * 16 + (l & 15);
      int off = row * 64 + ((ks * 4 + (l >> 4)) ^ (row & 7)) * 8;
      ah[m] = *reinterpret_cast<const bf16x8*>(&Ah[off]);
      al4[m] = *reinterpret_cast<const bf16x8*>(&Al[off]);
    }
#pragma unroll
    for (int n = 0; n < 4; ++n) {
      int row = wc * 64 + n * 16 + (l & 15);
      int off = row * 64 + ((ks * 4 + (l >> 4)) ^ (row & 7)) * 8;
      bh[n] = *reinterpret_cast<const bf16x8*>(&Bh[off]);
      bl4[n] = *reinterpret_cast<const bf16x8*>(&Bl[off]);
    }
#pragma unroll
    for (int m = 0; m < 4; ++m)
#pragma unroll
      for (int n = 0; n < 4; ++n) {
        acc[m][n] = MFMA16(ah[m], bh[n], acc[m][n]);
        acc[m][n] = MFMA16(ah[m], bl4[n], acc[m][n]);
        acc[m][n] = MFMA16(al4[m], bh[n], acc[m][n]);
      }
  }

  unsigned short* sb = st + (long)b * 512 * 512;
#pragma unroll
  for (int m = 0; m < 4; ++m)
#pragma unroll
    for (int n = 0; n < 4; ++n) {
      int i0 = iBase + wr * 64 + m * 16 + (l >> 4) * 4;
      int j = jBase + wc * 64 + n * 16 + (l & 15);
      unsigned short p[4];
#pragma unroll
      for (int reg = 0; reg < 4; ++reg) {
        float sg2 = 1.0f / (1.0f + __expf(-acc[m][n][reg]));
        p[reg] = f2bf(__expf(sg2));
      }
      *reinterpret_cast<uint2*>(&sb[(long)j * 512 + i0]) = *reinterpret_cast<uint2*>(p);
    }
}

// -------- K2b: per-row (j) sums of st -> rsum = 1/sum, attbias = (st.bias)/sum ----
__global__ __launch_bounds__(256) void k2b_rsum(const unsigned short* __restrict__ st,
                                                const float* __restrict__ bias,
                                                float* __restrict__ rsum,
                                                float* __restrict__ attbias) {
  int jg = blockIdx.x * 4 + (threadIdx.x >> 6);
  int l = threadIdx.x & 63;
  const unsigned short* row = st + (long)jg * 512 + l * 8;
  ushort4 u0 = *reinterpret_cast<const ushort4*>(row);
  ushort4 u1 = *reinterpret_cast<const ushort4*>(row + 4);
  float4 b0 = *reinterpret_cast<const float4*>(&bias[l * 8]);
  float4 b1 = *reinterpret_cast<const float4*>(&bias[l * 8 + 4]);
  float f0 = bf2f(u0.x), f1 = bf2f(u0.y), f2 = bf2f(u0.z), f3 = bf2f(u0.w);
  float f4 = bf2f(u1.x), f5 = bf2f(u1.y), f6 = bf2f(u1.z), f7 = bf2f(u1.w);
  float sum = (f0 + f1) + (f2 + f3) + ((f4 + f5) + (f6 + f7));
  float sumb = f0 * b0.x + f1 * b0.y + f2 * b0.z + f3 * b0.w +
               f4 * b1.x + f5 * b1.y + f6 * b1.z + f7 * b1.w;
#pragma unroll
  for (int off = 32; off > 0; off >>= 1) {
    sum += __shfl_down(sum, off);
    sumb += __shfl_down(sumb, off);
  }
  if (l == 0) {
    float r = 1.0f / sum;
    rsum[jg] = r;
    attbias[jg] = sumb * r;
  }
}

// -------- transpose + fp32->bf16 convert: out[c][r] = bf16(in[r][c]) --------
__global__ __launch_bounds__(256) void transpose_conv(const float* __restrict__ in,
                                                      unsigned short* __restrict__ out,
                                                      int inRows, int inCols,
                                                      long inBatch, long outBatch) {
  __shared__ unsigned short lt[64][65];
  int b = blockIdx.z;
  int r0 = blockIdx.y * 64;
  int c0 = blockIdx.x * 64;
  const float* I = in + (long)b * inBatch;
  unsigned short* O = out + (long)b * outBatch;
  int t = threadIdx.x;
  int cl = (t & 15) * 4;
  int rl = t >> 4;
#pragma unroll
  for (int rr = 0; rr < 4; ++rr) {
    int r = rl + rr * 16;
    float4 v = *reinterpret_cast<const float4*>(&I[(long)(r0 + r) * inCols + c0 + cl]);
    lt[cl + 0][r] = f2bf(v.x);
    lt[cl + 1][r] = f2bf(v.y);
    lt[cl + 2][r] = f2bf(v.z);
    lt[cl + 3][r] = f2bf(v.w);
  }
  __syncthreads();
#pragma unroll
  for (int rr = 0; rr < 4; ++rr) {
    int c = rl + rr * 16;
    unsigned short v[4] = {lt[c][cl], lt[c][cl + 1], lt[c][cl + 2], lt[c][cl + 3]};
    *reinterpret_cast<uint2*>(&O[(long)(c0 + c) * inRows + r0 + cl]) =
        *reinterpret_cast<uint2*>(&v[0]);
  }
}

// ======== 256x256 bf16 MFMA GEMM, BK=64, 8 waves, 8-PHASE schedule (m201) ========
template <int MODE>
__global__ __launch_bounds__(512) void mfma_nt256(const unsigned short* __restrict__ Abase,
                                                  const unsigned short* __restrict__ Bbase,
                                                  const float* __restrict__ rowscale,
                                                  unsigned short* __restrict__ Wout,
                                                  float* __restrict__ Fout) {
  __shared__ unsigned short As[2][256 * 64];
  __shared__ unsigned short Bs[2][256 * 64];
  const int t = threadIdx.x;
  const int l = t & 63;
  const int w = t >> 6;          // 0..7
  const int wr = w >> 2;         // 0..1  (M: 2 x 128)
  const int wc = w & 3;          // 0..3  (N: 4 x 64)

  const int cpx = gridDim.x >> 3;
  const int orig = blockIdx.x;
  const int lw = (orig & 7) * cpx + (orig >> 3);
  const int TPB_SH = (MODE == 0) ? 2 : 3;
  const int b = lw >> TPB_SH;
  const int tile = lw & ((1 << TPB_SH) - 1);
  const int mBase = (tile >> 1) * 256;
  const int nBase = (tile & 1) * 256;

  const unsigned short* Ag = Abase + ((MODE == 0) ? 0L : (long)b * (1024 * 512)) + (long)mBase * 512;
  const unsigned short* Bg = Bbase + (long)b * (512 * 512) + (long)nBase * 512;

  f32x4 acc[8][4];
#pragma unroll
  for (int m = 0; m < 8; ++m)
#pragma unroll
    for (int n = 0; n < 4; ++n) acc[m][n] = (f32x4){0.f, 0.f, 0.f, 0.f};

  const int srcslot = (l & 7) ^ (l >> 3);
  const int so0 = ((l >> 4) ^ (l & 7)) * 8;
  const int so1 = ((4 + (l >> 4)) ^ (l & 7)) * 8;

#define STG_A(p, tt, pr)                                                       \
  gld_lds16(Ag + (long)((pr) * 64 + w * 8 + (l >> 3)) * 512 + (tt) * 64 + srcslot * 8, \
            &As[p][((pr) * 64 + w * 8) * 64]);
#define STG_B(p, tt, pr)                                                       \
  gld_lds16(Bg + (long)((pr) * 64 + w * 8 + (l >> 3)) * 512 + (tt) * 64 + srcslot * 8, \
            &Bs[p][((pr) * 64 + w * 8) * 64]);

#define PHASE(p, q, STAGE_STMT, VMSTMT)                                        \
  {                                                                            \
    bf16x8 a00 = *reinterpret_cast<const bf16x8*>(                             \
        &As[p][(wr * 128 + (2 * (q)) * 16 + (l & 15)) * 64 + so0]);            \
    bf16x8 a01 = *reinterpret_cast<const bf16x8*>(                             \
        &As[p][(wr * 128 + (2 * (q)) * 16 + (l & 15)) * 64 + so1]);            \
    bf16x8 a10 = *reinterpret_cast<const bf16x8*>(                             \
        &As[p][(wr * 128 + (2 * (q) + 1) * 16 + (l & 15)) * 64 + so0]);        \
    bf16x8 a11 = *reinterpret_cast<const bf16x8*>(                             \
        &As[p][(wr * 128 + (2 * (q) + 1) * 16 + (l & 15)) * 64 + so1]);        \
    if ((q) == 0) {                                                            \
      _Pragma("unroll") for (int n = 0; n < 4; ++n) {                          \
        bfr0[n] = *reinterpret_cast<const bf16x8*>(                            \
            &Bs[p][(wc * 64 + n * 16 + (l & 15)) * 64 + so0]);                 \
        bfr1[n] = *reinterpret_cast<const bf16x8*>(                            \
            &Bs[p][(wc * 64 + n * 16 + (l & 15)) * 64 + so1]);                 \
      }                                                                        \
    }                                                                          \
    STAGE_STMT;                                                                \
    SCHED0();                                                                  \
    __builtin_amdgcn_s_barrier();                                              \
    LGKM0();                                                                   \
    __builtin_amdgcn_s_setprio(1);                                             \
    _Pragma("unroll") for (int n = 0; n < 4; ++n) {                            \
      acc[2 * (q)][n] = MFMA16(a00, bfr0[n], acc[2 * (q)][n]);                 \
      acc[2 * (q)][n] = MFMA16(a01, bfr1[n], acc[2 * (q)][n]);                 \
      acc[2 * (q) + 1][n] = MFMA16(a10, bfr0[n], acc[2 * (q) + 1][n]);         \
      acc[2 * (q) + 1][n] = MFMA16(a11, bfr1[n], acc[2 * (q) + 1][n]);         \
    }                                                                          \
    __builtin_amdgcn_s_setprio(0);                                             \
    VMSTMT;                                                                    \
    NTBAR();                                                                   \
  }

  bf16x8 bfr0[4], bfr1[4];

  // prologue: buf0 <- tile0 (8 loads), buf1 <- B0,B1,Ha of tile1 (6 loads)
  STG_A(0, 0, 0); STG_A(0, 0, 1); STG_A(0, 0, 2); STG_A(0, 0, 3);
  STG_B(0, 0, 0); STG_B(0, 0, 1); STG_B(0, 0, 2); STG_B(0, 0, 3);
  STG_B(1, 1, 0); STG_B(1, 1, 1); STG_B(1, 1, 2); STG_B(1, 1, 3);
  STG_A(1, 1, 0); STG_A(1, 1, 2);
  VMW(6);
  NTBAR();

  for (int it = 0; it < 4; ++it) {
    const int t1 = 2 * it + 1;
    const int t2 = (2 * it + 2 < 8) ? 2 * it + 2 : 7;
    const int t3 = (2 * it + 3 < 8) ? 2 * it + 3 : 7;
    PHASE(0, 0, { STG_A(1, t1, 1); STG_A(1, t1, 3); }, );
    PHASE(0, 1, { STG_B(0, t2, 0); STG_B(0, t2, 1); }, VMW(10));
    PHASE(0, 2, { STG_B(0, t2, 2); STG_B(0, t2, 3); }, );
    PHASE(0, 3, { STG_A(0, t2, 0); STG_A(0, t2, 2); }, VMW(8));
    PHASE(1, 0, { STG_A(0, t2, 1); STG_A(0, t2, 3); }, );
    PHASE(1, 1, { STG_B(1, t3, 0); STG_B(1, t3, 1); }, VMW(10));
    PHASE(1, 2, { STG_B(1, t3, 2); STG_B(1, t3, 3); }, );
    PHASE(1, 3, { STG_A(1, t3, 0); STG_A(1, t3, 2); }, VMW(8));
  }
#undef PHASE
#undef STG_A
#undef STG_B

  if (MODE == 0) {
    unsigned short* W = Wout + (long)b * (512 * 512);
#pragma unroll
    for (int n = 0; n < 4; ++n) {
      int j = nBase + wc * 64 + n * 16 + (l & 15);
      float rs = rowscale[b * 512 + j];
#pragma unroll
      for (int m = 0; m < 8; ++m) {
        int c0 = mBase + wr * 128 + m * 16 + (l >> 4) * 4;
        unsigned short p[4];
#pragma unroll
        for (int reg = 0; reg < 4; ++reg) p[reg] = f2bf(acc[m][n][reg] * rs);
        *reinterpret_cast<uint2*>(&W[(long)j * 512 + c0]) = *reinterpret_cast<uint2*>(p);
      }
    }
  } else {
    float* O = Fout + (long)b * (512 * 1024);
#pragma unroll
    for (int n = 0; n < 4; ++n) {
      int j = nBase + wc * 64 + n * 16 + (l & 15);
      float ab = rowscale[b * 512 + j];
#pragma unroll
      for (int m = 0; m < 8; ++m) {
        int n0 = mBase + wr * 128 + m * 16 + (l >> 4) * 4;
        *reinterpret_cast<float4*>(&O[(long)j * 1024 + n0]) =
            make_float4(acc[m][n][0] + ab, acc[m][n][1] + ab,
                        acc[m][n][2] + ab, acc[m][n][3] + ab);
      }
    }
  }
}

extern "C" void kernel_launch(void* const* d_in, const int* in_sizes, int n_in,
                              void* d_out, int out_size, void* d_ws, size_t ws_size,
                              hipStream_t stream) {
  const float* x  = (const float*)d_in[0];
  const float* Qm = (const float*)d_in[1];
  const float* Km = (const float*)d_in[2];
  const float* vw = (const float*)d_in[3];
  const float* vb = (const float*)d_in[4];
  float* out = (float*)d_out;

  float* ws = (float*)d_ws;
  unsigned short* qkh  = (unsigned short*)ws;                         // 4,194,304 ush
  unsigned short* qkl  = qkh + 4194304;                               // 4,194,304 ush
  unsigned short* st   = (unsigned short*)(ws + 4194304);             // spans 8,388,608 f
  unsigned short* weff = (unsigned short*)(ws + 4194304 + 8388608);   // spans 8,388,608 f
  unsigned short* xbT  = (unsigned short*)(ws + 4194304 + 16777216);  // spans 16,777,216 f
  unsigned short* vwT  = (unsigned short*)(ws + 4194304 + 33554432);  // spans 131,072 f
  unsigned short* qkTh = (unsigned short*)(ws + 4194304 + 33554432 + 131072);  // 65,536 f
  unsigned short* qkTl = qkTh + 131072;                               // 65,536 f
  float* rsum    = ws + 4194304 + 33554432 + 131072 + 131072;         // 32,768 f
  float* attbias = rsum + 32768;                                      // 32,768 f

  // T2: vwT[c][i] = bf16(vw[i][c])
  transpose_conv<<<dim3(8, 8, 1), 256, 0, stream>>>(vw, vwT, 512, 512, 0L, 0L);
  // T3: split-transposed [Qm|Km] -> qkTh/qkTl [128][1024]
  qkm_split<<<dim3(16, 2), 256, 0, stream>>>(Qm, Km, qkTh, qkTl);
  // K1: qkh/qkl = split(x @ [Qm|Km]) + fused xbT transpose (single-Tt, 3 blk/CU)
  k1_mfma<<<512, 256, 0, stream>>>(x, qkTh, qkTl, qkh, qkl, xbT);
  // K2a: st[b,j,i] = exp(sigmoid(q_i . k_j)), gld_lds staging of qkh/qkl
  k2a_mfma<<<1024, 256, 0, stream>>>(qkh, qkl, st);
  // K2b: rsum, attbias
  k2b_rsum<<<8192, 256, 0, stream>>>(st, vb, rsum, attbias);
  // K3: weff = diag(rsum) . st . Vw   (A=vwT, B=st), 4 tiles/b
  mfma_nt256<0><<<256, 512, 0, stream>>>(vwT, st, rsum, weff, nullptr);
  // K4: out = weff . xf + attbias     (A=xbT, B=weff), 8 tiles/b
  mfma_nt256<1><<<512, 512, 0, stream>>>(xbT, weff, attbias, nullptr, out);
}

// Round 18
// 182.637 us; speedup vs baseline: 1.3356x; 1.0151x over previous
//
#include <hip/hip_runtime.h>

typedef __attribute__((ext_vector_type(8))) short bf16x8;
typedef __attribute__((ext_vector_type(4))) float f32x4;

__device__ __forceinline__ unsigned short f2bf(float f) {
  unsigned u = __builtin_bit_cast(unsigned, f);
  unsigned r = (u + 0x7FFFu + ((u >> 16) & 1u)) >> 16;
  return (unsigned short)r;
}
__device__ __forceinline__ float bf2f(unsigned short h) {
  return __builtin_bit_cast(float, (unsigned)h << 16);
}
__device__ __forceinline__ unsigned pack2(unsigned short a, unsigned short b) {
  return (unsigned)a | ((unsigned)b << 16);
}

__device__ __forceinline__ void gld_lds16(const void* g, void* l) {
  __builtin_amdgcn_global_load_lds(
      (const __attribute__((address_space(1))) unsigned int*)g,
      (__attribute__((address_space(3))) unsigned int*)l, 16, 0, 0);
}

#define SCHED0() __builtin_amdgcn_sched_barrier(0)
#define NTBAR() do { SCHED0(); __builtin_amdgcn_s_barrier(); SCHED0(); } while (0)
#define VMW(N) do { asm volatile("s_waitcnt vmcnt(" #N ")" ::: "memory"); SCHED0(); } while (0)
#define LGKM0() do { asm volatile("s_waitcnt lgkmcnt(0)" ::: "memory"); SCHED0(); } while (0)
#define MFMA16(a, b, c) __builtin_amdgcn_mfma_f32_16x16x32_bf16(a, b, c, 0, 0, 0)

// split 8 fp32 -> hi/lo bf16, store as uint4 pair; return packed hi words
__device__ __forceinline__ uint4 split8_store_h(float4 v0, float4 v1,
                                                unsigned short* Hdst,
                                                unsigned short* Ldst) {
  float f[8] = {v0.x, v0.y, v0.z, v0.w, v1.x, v1.y, v1.z, v1.w};
  unsigned short hh[8], ll[8];
#pragma unroll
  for (int i = 0; i < 8; ++i) {
    hh[i] = f2bf(f[i]);
    ll[i] = f2bf(f[i] - bf2f(hh[i]));
  }
  uint4 hv = make_uint4(pack2(hh[0], hh[1]), pack2(hh[2], hh[3]),
                        pack2(hh[4], hh[5]), pack2(hh[6], hh[7]));
  *reinterpret_cast<uint4*>(Hdst) = hv;
  *reinterpret_cast<uint4*>(Ldst) = make_uint4(pack2(ll[0], ll[1]), pack2(ll[2], ll[3]),
                                               pack2(ll[4], ll[5]), pack2(ll[6], ll[7]));
  return hv;
}

// -------- transpose + fp32->bf16 convert: out[c][r] = bf16(in[r][c]) --------
__global__ __launch_bounds__(256) void transpose_conv(const float* __restrict__ in,
                                                      unsigned short* __restrict__ out,
                                                      int inRows, int inCols,
                                                      long inBatch, long outBatch) {
  __shared__ unsigned short lt[64][65];
  int b = blockIdx.z;
  int r0 = blockIdx.y * 64;
  int c0 = blockIdx.x * 64;
  const float* I = in + (long)b * inBatch;
  unsigned short* O = out + (long)b * outBatch;
  int t = threadIdx.x;
  int cl = (t & 15) * 4;
  int rl = t >> 4;
#pragma unroll
  for (int rr = 0; rr < 4; ++rr) {
    int r = rl + rr * 16;
    float4 v = *reinterpret_cast<const float4*>(&I[(long)(r0 + r) * inCols + c0 + cl]);
    lt[cl + 0][r] = f2bf(v.x);
    lt[cl + 1][r] = f2bf(v.y);
    lt[cl + 2][r] = f2bf(v.z);
    lt[cl + 3][r] = f2bf(v.w);
  }
  __syncthreads();
#pragma unroll
  for (int rr = 0; rr < 4; ++rr) {
    int c = rl + rr * 16;
    unsigned short v[4] = {lt[c][cl], lt[c][cl + 1], lt[c][cl + 2], lt[c][cl + 3]};
    *reinterpret_cast<uint2*>(&O[(long)(c0 + c) * inRows + r0 + cl]) =
        *reinterpret_cast<uint2*>(&v[0]);
  }
}

// -------- QB prep: Th/Tl[d][k] = split-bf16 of [Qm | Km] column d --------
__global__ __launch_bounds__(256) void qkm_split(const float* __restrict__ Qm,
                                                 const float* __restrict__ Km,
                                                 unsigned short* __restrict__ Th,
                                                 unsigned short* __restrict__ Tl) {
  __shared__ float lt[64][65];
  int k0 = blockIdx.x * 64;
  int half = blockIdx.y;
  const float* M = half ? Km : Qm;
  int t = threadIdx.x;
  int cl = (t & 15) * 4;
  int rl = t >> 4;
#pragma unroll
  for (int rr = 0; rr < 4; ++rr) {
    int r = rl + rr * 16;
    float4 v = *reinterpret_cast<const float4*>(&M[(long)(k0 + r) * 64 + cl]);
    lt[cl + 0][r] = v.x;
    lt[cl + 1][r] = v.y;
    lt[cl + 2][r] = v.z;
    lt[cl + 3][r] = v.w;
  }
  __syncthreads();
#pragma unroll
  for (int rr = 0; rr < 4; ++rr) {
    int c = rl + rr * 16;
    unsigned short h[4], lo[4];
#pragma unroll
    for (int i = 0; i < 4; ++i) {
      float f = lt[c][cl + i];
      h[i] = f2bf(f);
      lo[i] = f2bf(f - bf2f(h[i]));
    }
    *reinterpret_cast<uint2*>(&Th[(long)(half * 64 + c) * 1024 + k0 + cl]) =
        make_uint2(pack2(h[0], h[1]), pack2(h[2], h[3]));
    *reinterpret_cast<uint2*>(&Tl[(long)(half * 64 + c) * 1024 + k0 + cl]) =
        make_uint2(pack2(lo[0], lo[1]), pack2(lo[2], lo[3]));
  }
}

// -------- K1: qk split-bf16 out + fused x-transpose, single-Tt ----------------
__global__ __launch_bounds__(256) void k1_mfma(const float* __restrict__ x,
                                               const unsigned short* __restrict__ Th,
                                               const unsigned short* __restrict__ Tl,
                                               unsigned short* __restrict__ qkh,
                                               unsigned short* __restrict__ qkl,
                                               unsigned short* __restrict__ xbT) {
  __shared__ unsigned short Dh[2][128 * 32];
  __shared__ unsigned short Dl[2][128 * 32];
  __shared__ unsigned short Xh[2][64 * 32];
  __shared__ unsigned short Xl[2][64 * 32];
  __shared__ unsigned short Tt[32 * 72];
  const int t = threadIdx.x;
  const int l = t & 63;
  const int w = t >> 6;
  const int wr = w >> 1, wc = w & 1;
  const long mBase = (long)blockIdx.x * 64;
  const int b = blockIdx.x >> 3;
  const int cBase = (blockIdx.x & 7) * 64;

  f32x4 acc[4][2];
#pragma unroll
  for (int m = 0; m < 4; ++m)
#pragma unroll
    for (int n = 0; n < 2; ++n) acc[m][n] = (f32x4){0.f, 0.f, 0.f, 0.f};

  const int xrow_l = t >> 2;
  const int kslot = t & 3;
  const int xsl = kslot ^ ((t >> 3) & 3);
  const int srcslot = (l & 3) ^ ((l >> 3) & 3);
  const int frag_off = (l & 15) * 32 + ((((l >> 4) ^ (l >> 1)) & 3) * 8);
  const float* xrow = x + (mBase + xrow_l) * 1024;

#define K1_LOADX(r0, r1, tt)                                                  \
  {                                                                           \
    r0 = *reinterpret_cast<const float4*>(&xrow[(tt) * 32 + kslot * 8]);      \
    r1 = *reinterpret_cast<const float4*>(&xrow[(tt) * 32 + kslot * 8 + 4]);  \
  }

#define K1_STAGE_D(tt, p)                                                     \
  {                                                                           \
    _Pragma("unroll") for (int c = 0; c < 2; ++c) {                           \
      int ch = c * 4 + w;                                                     \
      int row = ch * 16 + (l >> 2);                                           \
      gld_lds16(Th + (long)row * 1024 + (tt) * 32 + srcslot * 8, &Dh[p][ch * 512]); \
      gld_lds16(Tl + (long)row * 1024 + (tt) * 32 + srcslot * 8, &Dl[p][ch * 512]); \
    }                                                                         \
  }

#define K1_COMPUTE(p)                                                         \
  {                                                                           \
    bf16x8 dh[4], dl[4], xh[2], xl[2];                                        \
    _Pragma("unroll") for (int m = 0; m < 4; ++m) {                           \
      dh[m] = *reinterpret_cast<const bf16x8*>(&Dh[p][(wr * 64 + m * 16) * 32 + frag_off]); \
      dl[m] = *reinterpret_cast<const bf16x8*>(&Dl[p][(wr * 64 + m * 16) * 32 + frag_off]); \
    }                                                                         \
    _Pragma("unroll") for (int n = 0; n < 2; ++n) {                           \
      xh[n] = *reinterpret_cast<const bf16x8*>(&Xh[p][(wc * 32 + n * 16) * 32 + frag_off]); \
      xl[n] = *reinterpret_cast<const bf16x8*>(&Xl[p][(wc * 32 + n * 16) * 32 + frag_off]); \
    }                                                                         \
    _Pragma("unroll") for (int m = 0; m < 4; ++m)                             \
        _Pragma("unroll") for (int n = 0; n < 2; ++n) {                       \
      acc[m][n] = MFMA16(dh[m], xh[n], acc[m][n]);                            \
      acc[m][n] = MFMA16(dh[m], xl[n], acc[m][n]);                            \
      acc[m][n] = MFMA16(dl[m], xh[n], acc[m][n]);                            \
    }                                                                         \
  }

#define K1_SCATTER(hv)                                                        \
  {                                                                           \
    unsigned short e[8] = {                                                   \
        (unsigned short)(hv.x & 0xffff), (unsigned short)(hv.x >> 16),        \
        (unsigned short)(hv.y & 0xffff), (unsigned short)(hv.y >> 16),        \
        (unsigned short)(hv.z & 0xffff), (unsigned short)(hv.z >> 16),        \
        (unsigned short)(hv.w & 0xffff), (unsigned short)(hv.w >> 16)};       \
    _Pragma("unroll") for (int i = 0; i < 8; ++i) {                           \
      int g = ((xrow_l >> 3) ^ i ^ kslot) & 7;                                \
      Tt[(kslot * 8 + i) * 72 + g * 8 + (xrow_l & 7)] = e[i];                 \
    }                                                                         \
  }

#define K1_WRITEBACK(kk)                                                      \
  {                                                                           \
    int n2 = t >> 3;                                                          \
    int g2 = t & 7;                                                           \
    int gs = (g2 ^ (n2 & 7) ^ (n2 >> 3)) & 7;                                 \
    uint4 vv = *reinterpret_cast<const uint4*>(&Tt[n2 * 72 + gs * 8]);        \
    *reinterpret_cast<uint4*>(                                                \
        &xbT[(long)b * 524288 + (long)((kk) + n2) * 512 + cBase + g2 * 8]) = vv; \
  }

  float4 xa0, xa1, xb0, xb1;
  uint4 hva, hvb;

  K1_LOADX(xa0, xa1, 0);
  K1_STAGE_D(0, 0);
  K1_LOADX(xb0, xb1, 1);
  hva = split8_store_h(xa0, xa1, &Xh[0][xrow_l * 32 + xsl * 8], &Xl[0][xrow_l * 32 + xsl * 8]);
  K1_SCATTER(hva);
  K1_STAGE_D(1, 1);
  VMW(6);
  LGKM0();
  NTBAR();

  for (int kt = 0; kt < 32; kt += 2) {
    {
      const int tn = (kt + 2 < 32) ? kt + 2 : 31;
      K1_COMPUTE(0);
      K1_WRITEBACK(kt * 32);
      K1_LOADX(xa0, xa1, tn);
      hvb = split8_store_h(xb0, xb1, &Xh[1][xrow_l * 32 + xsl * 8], &Xl[1][xrow_l * 32 + xsl * 8]);
      LGKM0();
      NTBAR();
      K1_SCATTER(hvb);
      K1_STAGE_D(tn, 0);
      LGKM0();
      VMW(7);
      NTBAR();
    }
    {
      const int tn = (kt + 3 < 32) ? kt + 3 : 31;
      K1_COMPUTE(1);
      K1_WRITEBACK((kt + 1) * 32);
      K1_LOADX(xb0, xb1, tn);
      hva = split8_store_h(xa0, xa1, &Xh[0][xrow_l * 32 + xsl * 8], &Xl[0][xrow_l * 32 + xsl * 8]);
      LGKM0();
      NTBAR();
      K1_SCATTER(hva);
      K1_STAGE_D(tn, 1);
      LGKM0();
      VMW(7);
      NTBAR();
    }
  }

#pragma unroll
  for (int m = 0; m < 4; ++m)
#pragma unroll
    for (int n = 0; n < 2; ++n) {
      int d0 = wr * 64 + m * 16 + (l >> 4) * 4;
      long xr = mBase + wc * 32 + n * 16 + (l & 15);
      unsigned short h4[4], l4[4];
#pragma unroll
      for (int reg = 0; reg < 4; ++reg) {
        float v = acc[m][n][reg];
        h4[reg] = f2bf(v);
        l4[reg] = f2bf(v - bf2f(h4[reg]));
      }
      *reinterpret_cast<uint2*>(&qkh[xr * 128 + d0]) =
          make_uint2(pack2(h4[0], h4[1]), pack2(h4[2], h4[3]));
      *reinterpret_cast<uint2*>(&qkl[xr * 128 + d0]) =
          make_uint2(pack2(l4[0], l4[1]), pack2(l4[2], l4[3]));
    }
#undef K1_LOADX
#undef K1_STAGE_D
#undef K1_COMPUTE
#undef K1_SCATTER
#undef K1_WRITEBACK
}

// -------- K2a: st[b,j,i] = exp(sigmoid(q_i . k_j)) + fused row-partials ------
// Epilogue accumulates partial sums of st and st*bias over the block's 128-i
// range (bf16-rounded values, matching the st bytes), reduces over i-lane-
// groups via shfl_xor, writes per (b, i-tile*2+wr): psum/pbias[b][8][512].
// Deterministic (no atomics).
__global__ __launch_bounds__(256) void k2a_mfma(const unsigned short* __restrict__ qkh,
                                                const unsigned short* __restrict__ qkl,
                                                const float* __restrict__ bias,
                                                unsigned short* __restrict__ st,
                                                float* __restrict__ psum,
                                                float* __restrict__ pbias) {
  __shared__ unsigned short Ah[128 * 64];
  __shared__ unsigned short Al[128 * 64];
  __shared__ unsigned short Bh[128 * 64];
  __shared__ unsigned short Bl[128 * 64];
  const int t = threadIdx.x;
  const int l = t & 63;
  const int w = t >> 6;
  const int wr = w >> 1, wc = w & 1;

  const int cpx = gridDim.x >> 3;
  const int orig = blockIdx.x;
  const int lw = (orig & 7) * cpx + (orig >> 3);
  const int b = lw >> 4;
  const int tile = lw & 15;
  const int iBase = (tile >> 2) * 128;
  const int jBase = (tile & 3) * 128;
  const long bq = (long)b * 512;

  const int sg = (l & 7) ^ (l >> 3);
#pragma unroll
  for (int c4 = 0; c4 < 4; ++c4) {
    int rb = w * 32 + c4 * 8;
    long rowA = bq + iBase + rb + (l >> 3);
    long rowB = bq + jBase + rb + (l >> 3);
    gld_lds16(qkh + rowA * 128 + sg * 8, &Ah[rb * 64]);
    gld_lds16(qkl + rowA * 128 + sg * 8, &Al[rb * 64]);
    gld_lds16(qkh + rowB * 128 + 64 + sg * 8, &Bh[rb * 64]);
    gld_lds16(qkl + rowB * 128 + 64 + sg * 8, &Bl[rb * 64]);
  }
  __syncthreads();

  f32x4 acc[4][4];
#pragma unroll
  for (int m = 0; m < 4; ++m)
#pragma unroll
    for (int n = 0; n < 4; ++n) acc[m][n] = (f32x4){0.f, 0.f, 0.f, 0.f};

#pragma unroll
  for (int ks = 0; ks < 2; ++ks) {
    bf16x8 ah[4], al4[4], bh[4], bl4[4];
#pragma unroll
    for (int m = 0; m < 4; ++m) {
      int row = wr * 64 + m * 16 + (l & 15);
      int off = row * 64 + ((ks * 4 + (l >> 4)) ^ (row & 7)) * 8;
      ah[m] = *reinterpret_cast<const bf16x8*>(&Ah[off]);
      al4[m] = *reinterpret_cast<const bf16x8*>(&Al[off]);
    }
#pragma unroll
    for (int n = 0; n < 4; ++n) {
      int row = wc * 64 + n * 16 + (l & 15);
      int off = row * 64 + ((ks * 4 + (l >> 4)) ^ (row & 7)) * 8;
      bh[n] = *reinterpret_cast<const bf16x8*>(&Bh[off]);
      bl4[n] = *reinterpret_cast<const bf16x8*>(&Bl[off]);
    }
#pragma unroll
    for (int m = 0; m < 4; ++m)
#pragma unroll
      for (int n = 0; n < 4; ++n) {
        acc[m][n] = MFMA16(ah[m], bh[n], acc[m][n]);
        acc[m][n] = MFMA16(ah[m], bl4[n], acc[m][n]);
        acc[m][n] = MFMA16(al4[m], bh[n], acc[m][n]);
      }
  }

  unsigned short* sb = st + (long)b * 512 * 512;
  float srow[4] = {0.f, 0.f, 0.f, 0.f};
  float sbias[4] = {0.f, 0.f, 0.f, 0.f};
#pragma unroll
  for (int m = 0; m < 4; ++m) {
    float4 vbm = *reinterpret_cast<const float4*>(&bias[iBase + wr * 64 + m * 16 + (l >> 4) * 4]);
    float vb4[4] = {vbm.x, vbm.y, vbm.z, vbm.w};
#pragma unroll
    for (int n = 0; n < 4; ++n) {
      int i0 = iBase + wr * 64 + m * 16 + (l >> 4) * 4;
      int j = jBase + wc * 64 + n * 16 + (l & 15);
      unsigned short p[4];
#pragma unroll
      for (int reg = 0; reg < 4; ++reg) {
        float sg2 = 1.0f / (1.0f + __expf(-acc[m][n][reg]));
        p[reg] = f2bf(__expf(sg2));
        float val = bf2f(p[reg]);
        srow[n] += val;
        sbias[n] += val * vb4[reg];
      }
      *reinterpret_cast<uint2*>(&sb[(long)j * 512 + i0]) = *reinterpret_cast<uint2*>(p);
    }
  }
  // reduce over the 4 i-lane-groups (lane bits 4,5)
#pragma unroll
  for (int n = 0; n < 4; ++n) {
    srow[n] += __shfl_xor(srow[n], 16);
    srow[n] += __shfl_xor(srow[n], 32);
    sbias[n] += __shfl_xor(sbias[n], 16);
    sbias[n] += __shfl_xor(sbias[n], 32);
  }
  if (l < 16) {
    int wrIdx = (iBase >> 6) + wr;  // 0..7
    long base = ((long)b * 8 + wrIdx) * 512 + jBase + wc * 64 + l;
#pragma unroll
    for (int n = 0; n < 4; ++n) {
      psum[base + n * 16] = srow[n];
      pbias[base + n * 16] = sbias[n];
    }
  }
}

// -------- K2b finish: rsum = 1/sum(partials), attbias = sum(pbias)*rsum -------
__global__ __launch_bounds__(256) void k2b_finish(const float* __restrict__ psum,
                                                  const float* __restrict__ pbias,
                                                  float* __restrict__ rsum,
                                                  float* __restrict__ attbias) {
  long j = (long)blockIdx.x * 256 + threadIdx.x;  // 0..32767
  long bb = j >> 9;
  int jj = (int)(j & 511);
  float s = 0.f, sbv = 0.f;
#pragma unroll
  for (int k = 0; k < 8; ++k) {
    s += psum[(bb * 8 + k) * 512 + jj];
    sbv += pbias[(bb * 8 + k) * 512 + jj];
  }
  float r = 1.0f / s;
  rsum[j] = r;
  attbias[j] = sbv * r;
}

// ======== 256x256 bf16 MFMA GEMM, BK=64, 8 waves, 8-PHASE schedule (m201) ========
template <int MODE>
__global__ __launch_bounds__(512) void mfma_nt256(const unsigned short* __restrict__ Abase,
                                                  const unsigned short* __restrict__ Bbase,
                                                  const float* __restrict__ rowscale,
                                                  unsigned short* __restrict__ Wout,
                                                  float* __restrict__ Fout) {
  __shared__ unsigned short As[2][256 * 64];
  __shared__ unsigned short Bs[2][256 * 64];
  const int t = threadIdx.x;
  const int l = t & 63;
  const int w = t >> 6;          // 0..7
  const int wr = w >> 2;         // 0..1  (M: 2 x 128)
  const int wc = w & 3;          // 0..3  (N: 4 x 64)

  const int cpx = gridDim.x >> 3;
  const int orig = blockIdx.x;
  const int lw = (orig & 7) * cpx + (orig >> 3);
  const int TPB_SH = (MODE == 0) ? 2 : 3;
  const int b = lw >> TPB_SH;
  const int tile = lw & ((1 << TPB_SH) - 1);
  const int mBase = (tile >> 1) * 256;
  const int nBase = (tile & 1) * 256;

  const unsigned short* Ag = Abase + ((MODE == 0) ? 0L : (long)b * (1024 * 512)) + (long)mBase * 512;
  const unsigned short* Bg = Bbase + (long)b * (512 * 512) + (long)nBase * 512;

  f32x4 acc[8][4];
#pragma unroll
  for (int m = 0; m < 8; ++m)
#pragma unroll
    for (int n = 0; n < 4; ++n) acc[m][n] = (f32x4){0.f, 0.f, 0.f, 0.f};

  const int srcslot = (l & 7) ^ (l >> 3);
  const int so0 = ((l >> 4) ^ (l & 7)) * 8;
  const int so1 = ((4 + (l >> 4)) ^ (l & 7)) * 8;

#define STG_A(p, tt, pr)                                                       \
  gld_lds16(Ag + (long)((pr) * 64 + w * 8 + (l >> 3)) * 512 + (tt) * 64 + srcslot * 8, \
            &As[p][((pr) * 64 + w * 8) * 64]);
#define STG_B(p, tt, pr)                                                       \
  gld_lds16(Bg + (long)((pr) * 64 + w * 8 + (l >> 3)) * 512 + (tt) * 64 + srcslot * 8, \
            &Bs[p][((pr) * 64 + w * 8) * 64]);

#define PHASE(p, q, STAGE_STMT, VMSTMT)                                        \
  {                                                                            \
    bf16x8 a00 = *reinterpret_cast<const bf16x8*>(                             \
        &As[p][(wr * 128 + (2 * (q)) * 16 + (l & 15)) * 64 + so0]);            \
    bf16x8 a01 = *reinterpret_cast<const bf16x8*>(                             \
        &As[p][(wr * 128 + (2 * (q)) * 16 + (l & 15)) * 64 + so1]);            \
    bf16x8 a10 = *reinterpret_cast<const bf16x8*>(                             \
        &As[p][(wr * 128 + (2 * (q) + 1) * 16 + (l & 15)) * 64 + so0]);        \
    bf16x8 a11 = *reinterpret_cast<const bf16x8*>(                             \
        &As[p][(wr * 128 + (2 * (q) + 1) * 16 + (l & 15)) * 64 + so1]);        \
    if ((q) == 0) {                                                            \
      _Pragma("unroll") for (int n = 0; n < 4; ++n) {                          \
        bfr0[n] = *reinterpret_cast<const bf16x8*>(                            \
            &Bs[p][(wc * 64 + n * 16 + (l & 15)) * 64 + so0]);                 \
        bfr1[n] = *reinterpret_cast<const bf16x8*>(                            \
            &Bs[p][(wc * 64 + n * 16 + (l & 15)) * 64 + so1]);                 \
      }                                                                        \
    }                                                                          \
    STAGE_STMT;                                                                \
    SCHED0();                                                                  \
    __builtin_amdgcn_s_barrier();                                              \
    LGKM0();                                                                   \
    __builtin_amdgcn_s_setprio(1);                                             \
    _Pragma("unroll") for (int n = 0; n < 4; ++n) {                            \
      acc[2 * (q)][n] = MFMA16(a00, bfr0[n], acc[2 * (q)][n]);                 \
      acc[2 * (q)][n] = MFMA16(a01, bfr1[n], acc[2 * (q)][n]);                 \
      acc[2 * (q) + 1][n] = MFMA16(a10, bfr0[n], acc[2 * (q) + 1][n]);         \
      acc[2 * (q) + 1][n] = MFMA16(a11, bfr1[n], acc[2 * (q) + 1][n]);         \
    }                                                                          \
    __builtin_amdgcn_s_setprio(0);                                             \
    VMSTMT;                                                                    \
    NTBAR();                                                                   \
  }

  bf16x8 bfr0[4], bfr1[4];

  // prologue: buf0 <- tile0 (8 loads), buf1 <- B0,B1,Ha of tile1 (6 loads)
  STG_A(0, 0, 0); STG_A(0, 0, 1); STG_A(0, 0, 2); STG_A(0, 0, 3);
  STG_B(0, 0, 0); STG_B(0, 0, 1); STG_B(0, 0, 2); STG_B(0, 0, 3);
  STG_B(1, 1, 0); STG_B(1, 1, 1); STG_B(1, 1, 2); STG_B(1, 1, 3);
  STG_A(1, 1, 0); STG_A(1, 1, 2);
  VMW(6);
  NTBAR();

  for (int it = 0; it < 4; ++it) {
    const int t1 = 2 * it + 1;
    const int t2 = (2 * it + 2 < 8) ? 2 * it + 2 : 7;
    const int t3 = (2 * it + 3 < 8) ? 2 * it + 3 : 7;
    PHASE(0, 0, { STG_A(1, t1, 1); STG_A(1, t1, 3); }, );
    PHASE(0, 1, { STG_B(0, t2, 0); STG_B(0, t2, 1); }, VMW(10));
    PHASE(0, 2, { STG_B(0, t2, 2); STG_B(0, t2, 3); }, );
    PHASE(0, 3, { STG_A(0, t2, 0); STG_A(0, t2, 2); }, VMW(8));
    PHASE(1, 0, { STG_A(0, t2, 1); STG_A(0, t2, 3); }, );
    PHASE(1, 1, { STG_B(1, t3, 0); STG_B(1, t3, 1); }, VMW(10));
    PHASE(1, 2, { STG_B(1, t3, 2); STG_B(1, t3, 3); }, );
    PHASE(1, 3, { STG_A(1, t3, 0); STG_A(1, t3, 2); }, VMW(8));
  }
#undef PHASE
#undef STG_A
#undef STG_B

  if (MODE == 0) {
    unsigned short* W = Wout + (long)b * (512 * 512);
#pragma unroll
    for (int n = 0; n < 4; ++n) {
      int j = nBase + wc * 64 + n * 16 + (l & 15);
      float rs = rowscale[b * 512 + j];
#pragma unroll
      for (int m = 0; m < 8; ++m) {
        int c0 = mBase + wr * 128 + m * 16 + (l >> 4) * 4;
        unsigned short p[4];
#pragma unroll
        for (int reg = 0; reg < 4; ++reg) p[reg] = f2bf(acc[m][n][reg] * rs);
        *reinterpret_cast<uint2*>(&W[(long)j * 512 + c0]) = *reinterpret_cast<uint2*>(p);
      }
    }
  } else {
    float* O = Fout + (long)b * (512 * 1024);
#pragma unroll
    for (int n = 0; n < 4; ++n) {
      int j = nBase + wc * 64 + n * 16 + (l & 15);
      float ab = rowscale[b * 512 + j];
#pragma unroll
      for (int m = 0; m < 8; ++m) {
        int n0 = mBase + wr * 128 + m * 16 + (l >> 4) * 4;
        *reinterpret_cast<float4*>(&O[(long)j * 1024 + n0]) =
            make_float4(acc[m][n][0] + ab, acc[m][n][1] + ab,
                        acc[m][n][2] + ab, acc[m][n][3] + ab);
      }
    }
  }
}

extern "C" void kernel_launch(void* const* d_in, const int* in_sizes, int n_in,
                              void* d_out, int out_size, void* d_ws, size_t ws_size,
                              hipStream_t stream) {
  const float* x  = (const float*)d_in[0];
  const float* Qm = (const float*)d_in[1];
  const float* Km = (const float*)d_in[2];
  const float* vw = (const float*)d_in[3];
  const float* vb = (const float*)d_in[4];
  float* out = (float*)d_out;

  float* ws = (float*)d_ws;
  unsigned short* qkh  = (unsigned short*)ws;                         // 4,194,304 ush
  unsigned short* qkl  = qkh + 4194304;                               // 4,194,304 ush
  unsigned short* st   = (unsigned short*)(ws + 4194304);             // spans 8,388,608 f
  unsigned short* weff = (unsigned short*)(ws + 4194304 + 8388608);   // spans 8,388,608 f
  unsigned short* xbT  = (unsigned short*)(ws + 4194304 + 16777216);  // spans 16,777,216 f
  unsigned short* vwT  = (unsigned short*)(ws + 4194304 + 33554432);  // spans 131,072 f
  unsigned short* qkTh = (unsigned short*)(ws + 4194304 + 33554432 + 131072);  // 65,536 f
  unsigned short* qkTl = qkTh + 131072;                               // 65,536 f
  float* rsum    = ws + 4194304 + 33554432 + 131072 + 131072;         // 32,768 f
  float* attbias = rsum + 32768;                                      // 32,768 f
  float* psum    = attbias + 32768;                                   // 262,144 f
  float* pbias   = psum + 262144;                                     // 262,144 f

  // T2: vwT[c][i] = bf16(vw[i][c])
  transpose_conv<<<dim3(8, 8, 1), 256, 0, stream>>>(vw, vwT, 512, 512, 0L, 0L);
  // T3: split-transposed [Qm|Km] -> qkTh/qkTl [128][1024]
  qkm_split<<<dim3(16, 2), 256, 0, stream>>>(Qm, Km, qkTh, qkTl);
  // K1: qkh/qkl = split(x @ [Qm|Km]) + fused xbT transpose (single-Tt)
  k1_mfma<<<512, 256, 0, stream>>>(x, qkTh, qkTl, qkh, qkl, xbT);
  // K2a: st + fused row-partials (psum/pbias)
  k2a_mfma<<<1024, 256, 0, stream>>>(qkh, qkl, vb, st, psum, pbias);
  // K2b finish: rsum, attbias from partials (4 MB instead of 33.5 MB)
  k2b_finish<<<128, 256, 0, stream>>>(psum, pbias, rsum, attbias);
  // K3: weff = diag(rsum) . st . Vw   (A=vwT, B=st), 4 tiles/b
  mfma_nt256<0><<<256, 512, 0, stream>>>(vwT, st, rsum, weff, nullptr);
  // K4: out = weff . xf + attbias     (A=xbT, B=weff), 8 tiles/b
  mfma_nt256<1><<<512, 512, 0, stream>>>(xbT, weff, attbias, nullptr, out);
}